// Round 8
// baseline (574.159 us; speedup 1.0000x reference)
//
#include <hip/hip_runtime.h>
#include <hip/hip_bf16.h>
#include <math.h>

#define EPS 1e-5f

// ---------------------------------------------------------------------------
// L0: (5,256,192)->(8,128,96), K=4,S=2,P=1, +bias +ReLU. 2 px per thread,
// aligned float4 row loads, float2 stores. grid 1536, block 256.
// ci loop MUST stay unroll 1 (R6: full unroll -> VGPR 256 spill, 600MB scratch).
// ---------------------------------------------------------------------------
__global__ __launch_bounds__(256) void conv0(const float* __restrict__ in,
                                             const float* __restrict__ w,
                                             const float* __restrict__ bias,
                                             float* __restrict__ out)
{
    __shared__ float sW[5 * 8 * 16];   // [ci][co][16]
    __shared__ float sB[8];
    int t   = threadIdx.x;
    int n   = blockIdx.x / 24;
    int pxb = blockIdx.x % 24;
    for (int i = t; i < 640; i += 256) {
        int ci = i / 128;
        int r  = i % 128;
        int co = r / 16;
        int k  = r % 16;
        sW[i] = w[((size_t)co * 5 + ci) * 16 + k];
    }
    if (t < 8) sB[t] = bias[t];
    __syncthreads();

    int px0 = (pxb * 256 + t) * 2;
    int oh  = px0 / 96;
    int ow0 = px0 % 96;            // even
    int ih0 = oh * 2 - 1;
    int iwq = ow0 * 2;             // multiple of 4

    float acc[8][2];
#pragma unroll
    for (int j = 0; j < 8; ++j) { acc[j][0] = sB[j]; acc[j][1] = sB[j]; }

    const float* ib = in + (size_t)n * 5 * 256 * 192;
#pragma unroll 1
    for (int ci = 0; ci < 5; ++ci) {
        const float* plane = ib + (size_t)ci * 256 * 192;
#pragma unroll
        for (int kh = 0; kh < 4; ++kh) {
            int ih = ih0 + kh;
            float p[6];
            if ((unsigned)ih < 256u) {
                const float* row = plane + (size_t)ih * 192;
                float4 q = *(const float4*)(row + iwq);
                p[1] = q.x; p[2] = q.y; p[3] = q.z; p[4] = q.w;
                p[0] = (iwq >= 1)      ? row[iwq - 1] : 0.f;
                p[5] = (iwq + 4 < 192) ? row[iwq + 4] : 0.f;
            } else {
#pragma unroll
                for (int k2 = 0; k2 < 6; ++k2) p[k2] = 0.f;
            }
#pragma unroll
            for (int j = 0; j < 8; ++j) {
                const float4 wv = *(const float4*)(sW + (ci * 8 + j) * 16 + kh * 4);
                acc[j][0] = fmaf(p[0], wv.x, acc[j][0]);
                acc[j][0] = fmaf(p[1], wv.y, acc[j][0]);
                acc[j][0] = fmaf(p[2], wv.z, acc[j][0]);
                acc[j][0] = fmaf(p[3], wv.w, acc[j][0]);
                acc[j][1] = fmaf(p[2], wv.x, acc[j][1]);
                acc[j][1] = fmaf(p[3], wv.y, acc[j][1]);
                acc[j][1] = fmaf(p[4], wv.z, acc[j][1]);
                acc[j][1] = fmaf(p[5], wv.w, acc[j][1]);
            }
        }
    }
    float* ob = out + (size_t)n * 8 * 12288 + px0;
#pragma unroll
    for (int j = 0; j < 8; ++j) {
        float2 v;
        v.x = fmaxf(acc[j][0], 0.f);
        v.y = fmaxf(acc[j][1], 0.f);
        *(float2*)(ob + (size_t)j * 12288) = v;
    }
}

// ---------------------------------------------------------------------------
// L1/L2: K=4,S=2,P=1 conv with ZERO-PADDED LDS input tile (no bounds checks,
// no scattered global taps). 192 threads = exact out-row multiple.
// Block = (n, cg, pxb); tile = CIC ci x TH rows x (W+2) cols.
// ---------------------------------------------------------------------------
template<int CIN, int CIC, int CPT, int COUT, int H, int W>
__global__ __launch_bounds__(192) void conv42L(const float* __restrict__ in,
                                               const float* __restrict__ w,
                                               const float* __restrict__ bias,
                                               float* __restrict__ out, int relu)
{
    constexpr int OH   = H / 2, OW = W / 2;
    constexpr int NPX  = OH * OW;
    constexpr int ROWS = 192 / OW;        // out rows per block (exact)
    constexpr int TH   = 2 * ROWS + 2;    // input rows spanned
    constexpr int WP   = W + 2;
    constexpr int NCG  = COUT / CPT;
    constexpr int PXB  = NPX / 192;

    __shared__ float sT[CIC * TH * WP];
    __shared__ float sW[CPT * CIC * 16];

    int t   = threadIdx.x;
    int bx  = blockIdx.x;
    int pxb = bx % PXB;
    int cg  = (bx / PXB) % NCG;
    int n   = bx / (PXB * NCG);

    int oh0   = pxb * ROWS;
    int ih_lo = 2 * oh0 - 1;

    int ohl = t / OW;                 // local out row 0..ROWS-1
    int ow  = t % OW;
    int oh  = oh0 + ohl;

    float acc[CPT];
#pragma unroll
    for (int j = 0; j < CPT; ++j) acc[j] = bias[cg * CPT + j];

#pragma unroll 1
    for (int cc = 0; cc < CIN; cc += CIC) {
        if (cc) __syncthreads();
        // stage zero-padded tile
        for (int i = t; i < CIC * TH * WP; i += 192) {
            int ci  = i / (TH * WP);
            int r   = i % (TH * WP);
            int ihp = r / WP;
            int iwp = r % WP;
            int ih  = ih_lo + ihp;
            int iw  = iwp - 1;
            float v = 0.f;
            if ((unsigned)ih < (unsigned)H && (unsigned)iw < (unsigned)W)
                v = in[((size_t)(n * CIN + cc + ci) * H + ih) * W + iw];
            sT[i] = v;
        }
        // stage weights [ci][j][16]
        for (int i = t; i < CPT * CIC * 16; i += 192) {
            int ci = i / (CPT * 16);
            int r  = i % (CPT * 16);
            int j  = r / 16;
            int k  = r % 16;
            sW[i] = w[((size_t)(cg * CPT + j) * CIN + cc + ci) * 16 + k];
        }
        __syncthreads();

#pragma unroll 1
        for (int ci = 0; ci < CIC; ++ci) {
            const float* tp = sT + ci * TH * WP + (2 * ohl) * WP + 2 * ow;
            float p[16];
#pragma unroll
            for (int kh = 0; kh < 4; ++kh)
#pragma unroll
                for (int kw = 0; kw < 4; ++kw)
                    p[kh * 4 + kw] = tp[kh * WP + kw];
            const float* wp_ = sW + ci * CPT * 16;
#pragma unroll
            for (int j = 0; j < CPT; ++j) {
                const float* wj = wp_ + j * 16;
#pragma unroll
                for (int k = 0; k < 16; ++k) acc[j] = fmaf(p[k], wj[k], acc[j]);
            }
        }
    }

#pragma unroll
    for (int j = 0; j < CPT; ++j) {
        float v = acc[j];
        if (relu) v = fmaxf(v, 0.f);
        out[((size_t)(n * COUT + cg * CPT + j) * OH + oh) * OW + ow] = v;
    }
}

// ---------------------------------------------------------------------------
// L3: (32,32,24)->(64,16,12), K4 S2 P1, ci-split 4 chunks of 8, CPT=8, with
// zero-padded full-plane LDS tile (8 x 34 x 26). grid 2048 x 192. Partials.
// ---------------------------------------------------------------------------
__global__ __launch_bounds__(192) void conv_l3s(const float* __restrict__ in,
                                                const float* __restrict__ w,
                                                float* __restrict__ pbuf)
{
    __shared__ float sT[8 * 34 * 26];  // 7072 floats, padded planes
    __shared__ float sW[8 * 8 * 16];   // [ci][j][16]
    int t  = threadIdx.x;
    int b  = blockIdx.x;
    int cg = b & 7;
    int s  = (b >> 3) & 3;
    int n  = b >> 5;

    const float* ib = in + ((size_t)n * 32 + s * 8) * 768;
    for (int i = t; i < 8 * 884; i += 192) {
        int ci  = i / 884;
        int r   = i % 884;
        int ihp = r / 26;
        int iwp = r % 26;
        int ih  = ihp - 1;
        int iw  = iwp - 1;
        float v = 0.f;
        if ((unsigned)ih < 32u && (unsigned)iw < 24u)
            v = ib[ci * 768 + ih * 24 + iw];
        sT[i] = v;
    }
    for (int i = t; i < 1024; i += 192) {
        int ci = i >> 7;
        int r  = i & 127;
        int j  = r >> 4;
        int k  = r & 15;
        sW[i] = w[((size_t)(cg * 8 + j) * 32 + s * 8 + ci) * 16 + k];
    }
    __syncthreads();

    int oh = t / 12, ow = t % 12;
    float acc[8];
#pragma unroll
    for (int j = 0; j < 8; ++j) acc[j] = 0.f;

#pragma unroll 1
    for (int ci = 0; ci < 8; ++ci) {
        const float* tp = sT + ci * 884 + (2 * oh) * 26 + 2 * ow;
        float p[16];
#pragma unroll
        for (int kh = 0; kh < 4; ++kh)
#pragma unroll
            for (int kw = 0; kw < 4; ++kw)
                p[kh * 4 + kw] = tp[kh * 26 + kw];
        const float* wp = sW + ci * 128;
#pragma unroll
        for (int j = 0; j < 8; ++j) {
#pragma unroll
            for (int k = 0; k < 16; ++k)
                acc[j] = fmaf(p[k], wp[j * 16 + k], acc[j]);
        }
    }
    float* pb = pbuf + (((size_t)s * 64 + n) * 64 + cg * 8) * 192 + t;
#pragma unroll
    for (int j = 0; j < 8; ++j) pb[j * 192] = acc[j];
}

// ---------------------------------------------------------------------------
// L3 reduce: sum 4 splits + instance norm over 192 px + relu, write
// TRANSPOSED [co][px][n] for conv_l4. wave per (n,co). grid 1024, block 256.
// ---------------------------------------------------------------------------
__global__ __launch_bounds__(256) void reduce_norm_l3T(const float* __restrict__ pbuf,
                                                       float* __restrict__ dst_t)
{
    int gid  = blockIdx.x * blockDim.x + threadIdx.x;
    int wv   = gid >> 6;          // 0..4095 = n*64+co
    int lane = gid & 63;
    int n  = wv >> 6;
    int co = wv & 63;
    float tv[3];
#pragma unroll
    for (int k = 0; k < 3; ++k) {
        int i = lane + k * 64;
        float sum = 0.f;
#pragma unroll
        for (int s = 0; s < 4; ++s)
            sum += pbuf[((size_t)s * 4096 + wv) * 192 + i];
        tv[k] = sum;
    }
    float s1 = tv[0] + tv[1] + tv[2];
    float s2 = tv[0]*tv[0] + tv[1]*tv[1] + tv[2]*tv[2];
    for (int m = 32; m >= 1; m >>= 1) {
        s1 += __shfl_xor(s1, m);
        s2 += __shfl_xor(s2, m);
    }
    float mean = s1 * (1.f / 192.f);
    float var  = s2 * (1.f / 192.f) - mean * mean;
    float r = rsqrtf(var + EPS);
#pragma unroll
    for (int k = 0; k < 3; ++k) {
        int i = lane + k * 64;
        float y = fmaxf((tv[k] - mean) * r, 0.f);
        dst_t[((size_t)co * 192 + i) * 64 + n] = y;
    }
}

// ---------------------------------------------------------------------------
// Single-pass instance norm: register-cached float4. HW = TPB*VPT*4. In place.
// ---------------------------------------------------------------------------
template<int TPB, int VPT>
__global__ void inorm_blockv(float* __restrict__ data, int relu)
{
    const int HW = TPB * VPT * 4;
    float4* p = (float4*)(data + (size_t)blockIdx.x * HW);
    float4 v[VPT];
    float s = 0.f, q = 0.f;
#pragma unroll
    for (int k = 0; k < VPT; ++k) {
        v[k] = p[threadIdx.x + k * TPB];
        s += v[k].x + v[k].y + v[k].z + v[k].w;
        q += v[k].x*v[k].x + v[k].y*v[k].y + v[k].z*v[k].z + v[k].w*v[k].w;
    }
    for (int m2 = 32; m2 >= 1; m2 >>= 1) {
        s += __shfl_xor(s, m2);
        q += __shfl_xor(q, m2);
    }
    __shared__ float ss[TPB / 64], sq[TPB / 64], sm[2];
    int wave = threadIdx.x >> 6, lane = threadIdx.x & 63;
    if (lane == 0) { ss[wave] = s; sq[wave] = q; }
    __syncthreads();
    if (threadIdx.x == 0) {
        float a = 0.f, b2 = 0.f;
#pragma unroll
        for (int k = 0; k < TPB / 64; ++k) { a += ss[k]; b2 += sq[k]; }
        float mm = a / (float)HW;
        float vv = b2 / (float)HW - mm * mm;
        sm[0] = mm; sm[1] = rsqrtf(vv + EPS);
    }
    __syncthreads();
    float m = sm[0], r = sm[1];
#pragma unroll
    for (int k = 0; k < VPT; ++k) {
        float4 y;
        y.x = (v[k].x - m) * r; y.y = (v[k].y - m) * r;
        y.z = (v[k].z - m) * r; y.w = (v[k].w - m) * r;
        if (relu) {
            y.x = fmaxf(y.x, 0.f); y.y = fmaxf(y.y, 0.f);
            y.z = fmaxf(y.z, 0.f); y.w = fmaxf(y.w, 0.f);
        }
        p[threadIdx.x + k * TPB] = y;
    }
}

// ---------------------------------------------------------------------------
// L4: (64,16,12)->(128,8,6). Input transposed [ci][px(192)][n(64)].
// ---------------------------------------------------------------------------
__global__ __launch_bounds__(256) void conv_l4(const float* __restrict__ in_t,
                                               const float* __restrict__ w,
                                               float* __restrict__ pbuf)
{
    int t    = threadIdx.x;
    int lane = t & 63;                      // = n
    int gw   = __builtin_amdgcn_readfirstlane(blockIdx.x * 4 + (t >> 6)); // 0..1023
    int cog  = gw & 63;
    int cic  = (gw >> 6) & 7;
    int half = gw >> 9;
    int cc   = cic * 8;
    int co0  = cog * 2;
    int oh0  = half * 4;

    float acc[2][24];
#pragma unroll
    for (int j = 0; j < 2; ++j)
#pragma unroll
        for (int p = 0; p < 24; ++p) acc[j][p] = 0.f;

    const float* wp = w + ((size_t)co0 * 64 + cc) * 16;

#pragma unroll 1
    for (int ci = 0; ci < 8; ++ci) {
        const float* pl = in_t + (size_t)(cc + ci) * 192 * 64 + lane;
        float wr[2][16];
#pragma unroll
        for (int k = 0; k < 16; ++k) {
            wr[0][k] = wp[(0 * 64 + ci) * 16 + k];
            wr[1][k] = wp[(1 * 64 + ci) * 16 + k];
        }
#pragma unroll
        for (int kh = 0; kh < 4; ++kh) {
            float p[4][12];
#pragma unroll
            for (int o = 0; o < 4; ++o) {
                int ih = 2 * (oh0 + o) - 1 + kh;
                if ((unsigned)ih < 16u) {
#pragma unroll
                    for (int c = 0; c < 12; ++c)
                        p[o][c] = pl[(size_t)(ih * 12 + c) * 64];
                } else {
#pragma unroll
                    for (int c = 0; c < 12; ++c) p[o][c] = 0.f;
                }
            }
#pragma unroll
            for (int o = 0; o < 4; ++o)
#pragma unroll
                for (int ow = 0; ow < 6; ++ow) {
#pragma unroll
                    for (int kw = 0; kw < 4; ++kw) {
                        int iw = 2 * ow - 1 + kw;
                        if (iw < 0 || iw >= 12) continue;
                        float pv = p[o][iw];
                        acc[0][o * 6 + ow] = fmaf(pv, wr[0][kh * 4 + kw], acc[0][o * 6 + ow]);
                        acc[1][o * 6 + ow] = fmaf(pv, wr[1][kh * 4 + kw], acc[1][o * 6 + ow]);
                    }
                }
        }
    }

    float* pb = pbuf + ((size_t)(cic * 64 + lane) * 128 + co0) * 48 + oh0 * 6;
#pragma unroll
    for (int j = 0; j < 2; ++j) {
        float4* o4 = (float4*)(pb + j * 48);
#pragma unroll
        for (int q = 0; q < 6; ++q)
            o4[q] = make_float4(acc[j][q * 4 + 0], acc[j][q * 4 + 1],
                                acc[j][q * 4 + 2], acc[j][q * 4 + 3]);
    }
}

__global__ __launch_bounds__(256) void reduce_norm48(const float* __restrict__ pbuf,
                                                     float* __restrict__ out)
{
    int g  = blockIdx.x * blockDim.x + threadIdx.x;   // 8192 threads
    int co = g & 127;
    int n  = g >> 7;
    float s[48];
#pragma unroll
    for (int p = 0; p < 48; ++p) s[p] = 0.f;
#pragma unroll 1
    for (int c = 0; c < 8; ++c) {
        const float4* p4 = (const float4*)(pbuf + ((size_t)(c * 64 + n) * 128 + co) * 48);
#pragma unroll
        for (int q = 0; q < 12; ++q) {
            float4 a = p4[q];
            s[q * 4 + 0] += a.x; s[q * 4 + 1] += a.y;
            s[q * 4 + 2] += a.z; s[q * 4 + 3] += a.w;
        }
    }
    float m = 0.f;
#pragma unroll
    for (int p = 0; p < 48; ++p) m += s[p];
    m *= (1.f / 48.f);
    float q = 0.f;
#pragma unroll
    for (int p = 0; p < 48; ++p) { float d = s[p] - m; q += d * d; }
    q *= (1.f / 48.f);
    float r = rsqrtf(q + EPS);
    float4* o4 = (float4*)(out + ((size_t)n * 128 + co) * 48);
#pragma unroll
    for (int qq = 0; qq < 12; ++qq) {
        float4 v;
        v.x = fmaxf((s[qq * 4 + 0] - m) * r, 0.f);
        v.y = fmaxf((s[qq * 4 + 1] - m) * r, 0.f);
        v.z = fmaxf((s[qq * 4 + 2] - m) * r, 0.f);
        v.w = fmaxf((s[qq * 4 + 3] - m) * r, 0.f);
        o4[qq] = v;
    }
}

// ---------------------------------------------------------------------------
// L6/L7: (256,4,3)->(256,4,3), K=3,S=1,P=1. lane=n scheme.
// ---------------------------------------------------------------------------
__global__ __launch_bounds__(256) void conv_l67(const float* __restrict__ in,
                                                const float* __restrict__ w,
                                                float* __restrict__ pbuf)
{
    int t    = threadIdx.x;
    int gw   = __builtin_amdgcn_readfirstlane(blockIdx.x * 4 + (t >> 6));
    int lane = t & 63;
    int cic  = gw >> 6;
    int cog  = gw & 63;
    int cc   = cic * 16;
    int co0  = cog * 4;

    float acc[4][12];
#pragma unroll
    for (int j = 0; j < 4; ++j)
#pragma unroll
        for (int p = 0; p < 12; ++p) acc[j][p] = 0.f;

    const float* ip = in + ((size_t)lane * 256 + cc) * 12;
    const float* wp = w + ((size_t)co0 * 256 + cc) * 9;

#pragma unroll 2
    for (int ci = 0; ci < 16; ++ci) {
        float p[12];
        const float4* p4 = (const float4*)(ip + ci * 12);
        float4 a0 = p4[0], a1 = p4[1], a2 = p4[2];
        p[0] = a0.x; p[1] = a0.y; p[2]  = a0.z; p[3]  = a0.w;
        p[4] = a1.x; p[5] = a1.y; p[6]  = a1.z; p[7]  = a1.w;
        p[8] = a2.x; p[9] = a2.y; p[10] = a2.z; p[11] = a2.w;
#pragma unroll
        for (int j = 0; j < 4; ++j) {
            const float* wj = wp + ((size_t)j * 256 + ci) * 9;
            float wr[9];
#pragma unroll
            for (int k = 0; k < 9; ++k) wr[k] = wj[k];
#pragma unroll
            for (int oh = 0; oh < 4; ++oh)
#pragma unroll
                for (int ow = 0; ow < 3; ++ow)
#pragma unroll
                    for (int kh = 0; kh < 3; ++kh) {
                        int ih = oh - 1 + kh;
                        if (ih < 0 || ih >= 4) continue;
#pragma unroll
                        for (int kw = 0; kw < 3; ++kw) {
                            int iw = ow - 1 + kw;
                            if (iw < 0 || iw >= 3) continue;
                            acc[j][oh * 3 + ow] =
                                fmaf(p[ih * 3 + iw], wr[kh * 3 + kw], acc[j][oh * 3 + ow]);
                        }
                    }
        }
    }

    float* pb = pbuf + ((size_t)(cic * 64 + lane) * 256 + co0) * 12;
#pragma unroll
    for (int j = 0; j < 4; ++j) {
        float4* o4 = (float4*)(pb + j * 12);
        o4[0] = make_float4(acc[j][0], acc[j][1], acc[j][2],  acc[j][3]);
        o4[1] = make_float4(acc[j][4], acc[j][5], acc[j][6],  acc[j][7]);
        o4[2] = make_float4(acc[j][8], acc[j][9], acc[j][10], acc[j][11]);
    }
}

// ---------------------------------------------------------------------------
// L5: (128,8,6)->(256,4,3), K=4,S=2,P=1. lane=n scheme.
// ---------------------------------------------------------------------------
__global__ __launch_bounds__(256) void conv_l5(const float* __restrict__ in,
                                               const float* __restrict__ w,
                                               float* __restrict__ pbuf)
{
    int t    = threadIdx.x;
    int gw   = __builtin_amdgcn_readfirstlane(blockIdx.x * 4 + (t >> 6));
    int lane = t & 63;
    int cic  = gw >> 6;
    int cog  = gw & 63;
    int cc   = cic * 8;
    int co0  = cog * 4;

    float acc[4][12];
#pragma unroll
    for (int j = 0; j < 4; ++j)
#pragma unroll
        for (int p = 0; p < 12; ++p) acc[j][p] = 0.f;

    const float* ip = in + ((size_t)lane * 128 + cc) * 48;
    const float* wp = w + ((size_t)co0 * 128 + cc) * 16;

#pragma unroll 1
    for (int ci = 0; ci < 8; ++ci) {
        float p[48];
        const float4* p4 = (const float4*)(ip + ci * 48);
#pragma unroll
        for (int q = 0; q < 12; ++q) {
            float4 a = p4[q];
            p[q * 4 + 0] = a.x; p[q * 4 + 1] = a.y; p[q * 4 + 2] = a.z; p[q * 4 + 3] = a.w;
        }
#pragma unroll
        for (int j = 0; j < 4; ++j) {
            const float* wj = wp + ((size_t)j * 128 + ci) * 16;
            float wr[16];
#pragma unroll
            for (int k = 0; k < 16; ++k) wr[k] = wj[k];
#pragma unroll
            for (int oh = 0; oh < 4; ++oh)
#pragma unroll
                for (int ow = 0; ow < 3; ++ow) {
                    int ih0 = 2 * oh - 1, iw0 = 2 * ow - 1;
#pragma unroll
                    for (int kh = 0; kh < 4; ++kh) {
                        int ih = ih0 + kh;
                        if (ih < 0 || ih >= 8) continue;
#pragma unroll
                        for (int kw = 0; kw < 4; ++kw) {
                            int iw = iw0 + kw;
                            if (iw < 0 || iw >= 6) continue;
                            acc[j][oh * 3 + ow] =
                                fmaf(p[ih * 6 + iw], wr[kh * 4 + kw], acc[j][oh * 3 + ow]);
                        }
                    }
                }
        }
    }

    float* pb = pbuf + ((size_t)(cic * 64 + lane) * 256 + co0) * 12;
#pragma unroll
    for (int j = 0; j < 4; ++j) {
        float4* o4 = (float4*)(pb + j * 12);
        o4[0] = make_float4(acc[j][0], acc[j][1], acc[j][2],  acc[j][3]);
        o4[1] = make_float4(acc[j][4], acc[j][5], acc[j][6],  acc[j][7]);
        o4[2] = make_float4(acc[j][8], acc[j][9], acc[j][10], acc[j][11]);
    }
}

__global__ __launch_bounds__(256) void reduce_norm12(const float* __restrict__ pbuf,
                                                     float* __restrict__ out)
{
    int g  = blockIdx.x * blockDim.x + threadIdx.x;   // 16384 threads
    int co = g & 255;
    int n  = g >> 8;
    float s[12];
#pragma unroll
    for (int p = 0; p < 12; ++p) s[p] = 0.f;
#pragma unroll 1
    for (int c = 0; c < 16; ++c) {
        const float4* p4 = (const float4*)(pbuf + ((size_t)(c * 64 + n) * 256 + co) * 12);
        float4 a = p4[0], b = p4[1], d = p4[2];
        s[0] += a.x; s[1] += a.y; s[2]  += a.z; s[3]  += a.w;
        s[4] += b.x; s[5] += b.y; s[6]  += b.z; s[7]  += b.w;
        s[8] += d.x; s[9] += d.y; s[10] += d.z; s[11] += d.w;
    }
    float m = 0.f;
#pragma unroll
    for (int p = 0; p < 12; ++p) m += s[p];
    m *= (1.f / 12.f);
    float q = 0.f;
#pragma unroll
    for (int p = 0; p < 12; ++p) { float d = s[p] - m; q += d * d; }
    q *= (1.f / 12.f);
    float r = rsqrtf(q + EPS);
    float* op = out + ((size_t)n * 256 + co) * 12;
    float4* o4 = (float4*)op;
    float y[12];
#pragma unroll
    for (int p = 0; p < 12; ++p) y[p] = fmaxf((s[p] - m) * r, 0.f);
    o4[0] = make_float4(y[0], y[1], y[2],  y[3]);
    o4[1] = make_float4(y[4], y[5], y[6],  y[7]);
    o4[2] = make_float4(y[8], y[9], y[10], y[11]);
}

// maxpool (64,256,4,3) -> (64,512)
__global__ void pool_kernel(const float* __restrict__ in, float* __restrict__ out)
{
    int idx = blockIdx.x * blockDim.x + threadIdx.x;
    if (idx >= 64 * 512) return;
    int f = idx & 511;
    int n = idx >> 9;
    int c = f >> 1;
    int h = f & 1;
    const float* p = in + (((size_t)n * 256 + c) * 4 + h * 2) * 3;
    out[idx] = fmaxf(fmaxf(p[0], p[1]), fmaxf(p[3], p[4]));
}

__global__ void fc1_kernel(const float* __restrict__ in, const float* __restrict__ w,
                           const float* __restrict__ b, float* __restrict__ out)
{
    int idx = blockIdx.x * blockDim.x + threadIdx.x;
    if (idx >= 64 * 128) return;
    int j = idx & 127;
    int n = idx >> 7;
    const float* x  = in + n * 512;
    const float* wr = w + j * 512;
    float acc = b[j];
    for (int f = 0; f < 512; ++f) acc = fmaf(x[f], wr[f], acc);
    out[idx] = fmaxf(acc, 0.f);
}

__global__ void fc2_kernel(const float* __restrict__ in, const float* __restrict__ w,
                           const float* __restrict__ b, float* __restrict__ out)
{
    int idx = blockIdx.x * blockDim.x + threadIdx.x;
    if (idx >= 64 * 50) return;
    int k = idx % 50;
    int n = idx / 50;
    const float* x  = in + n * 128;
    const float* wr = w + k * 128;
    float acc = b[k];
    for (int f = 0; f < 128; ++f) acc = fmaf(x[f], wr[f], acc);
    out[idx] = tanhf(acc);
}

__global__ void loss_kernel(const float* __restrict__ pts, float* __restrict__ out)
{
    __shared__ float acc[4][64];
    int n = threadIdx.x;
    float rx = 0.f, ry = 0.f, cx = 0.f, cy = 0.f;
    {
        const float* g = pts + n * 50;
        for (int r = 0; r < 5; ++r)
            for (int j = 0; j < 3; ++j)
                for (int d = 0; d < 2; ++d) {
                    float a0 = g[(r * 5 + j) * 2 + d];
                    float a1 = g[(r * 5 + j + 1) * 2 + d];
                    float a2 = g[(r * 5 + j + 2) * 2 + d];
                    float d0 = (a1 - a0) * (a1 - a0);
                    float d1 = (a2 - a1) * (a2 - a1);
                    float t = fmaxf(0.08f, fabsf(d1 - d0));
                    if (d == 0) rx += t; else ry += t;
                }
        for (int r = 0; r < 5; ++r)
            for (int j = 0; j < 3; ++j)
                for (int d = 0; d < 2; ++d) {
                    float a0 = g[(j * 5 + r) * 2 + d];
                    float a1 = g[((j + 1) * 5 + r) * 2 + d];
                    float a2 = g[((j + 2) * 5 + r) * 2 + d];
                    float d0 = (a1 - a0) * (a1 - a0);
                    float d1 = (a2 - a1) * (a2 - a1);
                    float t = fmaxf(0.08f, fabsf(d1 - d0));
                    if (d == 0) cx += t; else cy += t;
                }
    }
    acc[0][n] = rx; acc[1][n] = ry; acc[2][n] = cx; acc[3][n] = cy;
    __syncthreads();
    if (n == 0) {
        float s0 = 0.f, s1 = 0.f, s2 = 0.f, s3 = 0.f;
        for (int i = 0; i < 64; ++i) {
            s0 += acc[0][i]; s1 += acc[1][i]; s2 += acc[2][i]; s3 += acc[3][i];
        }
        float inv = 1.0f / (64.0f * 15.0f);
        out[3200] = s0 * inv;
        out[3201] = s1 * inv;
        out[3202] = s2 * inv;
        out[3203] = s3 * inv;
        const float* g = pts;
        float rg = 0.f, cg = 0.f;
        for (int r = 0; r < 5; ++r)
            for (int j = 0; j < 3; ++j) {
                float x0 = g[(r * 5 + j) * 2],     y0 = g[(r * 5 + j) * 2 + 1];
                float x1 = g[(r * 5 + j + 1) * 2], y1 = g[(r * 5 + j + 1) * 2 + 1];
                float x2 = g[(r * 5 + j + 2) * 2], y2 = g[(r * 5 + j + 2) * 2 + 1];
                rg += fabsf((y1 - y0) * (x1 - x2) - (y1 - y2) * (x1 - x0));
            }
        for (int r = 0; r < 5; ++r)
            for (int j = 0; j < 3; ++j) {
                float x0 = g[(j * 5 + r) * 2],       y0 = g[(j * 5 + r) * 2 + 1];
                float x1 = g[((j + 1) * 5 + r) * 2], y1 = g[((j + 1) * 5 + r) * 2 + 1];
                float x2 = g[((j + 2) * 5 + r) * 2], y2 = g[((j + 2) * 5 + r) * 2 + 1];
                cg += fabsf((y1 - y0) * (x1 - x2) - (y1 - y2) * (x1 - x0));
            }
        out[3204] = fmaxf(rg, 0.02f);
        out[3205] = fmaxf(cg, 0.02f);
    }
}

extern "C" void kernel_launch(void* const* d_in, const int* in_sizes, int n_in,
                              void* d_out, int out_size, void* d_ws, size_t ws_size,
                              hipStream_t stream)
{
    const float* x = (const float*)d_in[0];
    const float* w[8], *bia[8];
    for (int i = 0; i < 6; ++i) { w[i] = (const float*)d_in[1 + 2 * i]; bia[i] = (const float*)d_in[2 + 2 * i]; }
    w[6] = (const float*)d_in[13]; bia[6] = (const float*)d_in[14];
    w[7] = (const float*)d_in[15]; bia[7] = (const float*)d_in[16];
    const float* fc1_w = (const float*)d_in[17];
    const float* fc1_b = (const float*)d_in[18];
    const float* fc2_w = (const float*)d_in[19];
    const float* fc2_b = (const float*)d_in[20];
    float* out = (float*)d_out;

    // workspace (floats):
    float* A      = (float*)d_ws;              // [0 .. 6291456)
    float* Bf     = A + 6291456;               // [6291456 .. 9437184)
    float* pooled = Bf + 3145728;
    float* fc1o   = pooled + 32768;
    float* pbuf3  = A + 1572864;               // L3 partials, 3145728 floats (inside A)
    float* At     = A;                         // L3 norm'd transposed out, 786432 floats
    float* l4out  = A + 1048576;               // 393216 floats
    float* pbuf   = A + 3145728;               // L4-L7 partials, <=3145728 floats

    const int N = 64;

    // ---- L0: conv+bias+relu, then norm ----
    conv0<<<1536, 256, 0, stream>>>(x, w[0], bia[0], A);
    inorm_blockv<256, 12><<<N * 8, 256, 0, stream>>>(A, 0);           // HW=12288

    // ---- L1: (8,128,96)->(16,64,48), LDS-tiled ----
    conv42L<8, 8, 8, 16, 128, 96><<<2048, 192, 0, stream>>>(A, w[1], bia[1], Bf, 0);
    inorm_blockv<256, 3><<<N * 16, 256, 0, stream>>>(Bf, 1);          // HW=3072

    // ---- L2: (16,64,48)->(32,32,24), LDS-tiled; out -> A[0..1572864) ----
    conv42L<16, 8, 8, 32, 64, 48><<<1024, 192, 0, stream>>>(Bf, w[2], bia[2], A, 0);
    inorm_blockv<192, 1><<<N * 32, 192, 0, stream>>>(A, 1);           // HW=768

    // ---- L3: LDS-tiled ci-split conv + fused reduce/norm/relu, transposed out ----
    conv_l3s<<<2048, 192, 0, stream>>>(A, w[3], pbuf3);
    reduce_norm_l3T<<<1024, 256, 0, stream>>>(pbuf3, At);

    // ---- L4 ----
    conv_l4<<<256, 256, 0, stream>>>(At, w[4], pbuf);
    reduce_norm48<<<32, 256, 0, stream>>>(pbuf, l4out);

    // ---- L5 ----
    conv_l5<<<256, 256, 0, stream>>>(l4out, w[5], pbuf);
    reduce_norm12<<<64, 256, 0, stream>>>(pbuf, Bf);

    // ---- L6 ----
    conv_l67<<<256, 256, 0, stream>>>(Bf, w[6], pbuf);
    reduce_norm12<<<64, 256, 0, stream>>>(pbuf, A);

    // ---- L7 ----
    conv_l67<<<256, 256, 0, stream>>>(A, w[7], pbuf);
    float* l7out = Bf + 262144;
    reduce_norm12<<<64, 256, 0, stream>>>(pbuf, l7out);

    pool_kernel<<<(64 * 512 + 255) / 256, 256, 0, stream>>>(l7out, pooled);
    fc1_kernel<<<(64 * 128 + 255) / 256, 256, 0, stream>>>(pooled, fc1_w, fc1_b, fc1o);
    fc2_kernel<<<(64 * 50 + 255) / 256, 256, 0, stream>>>(fc1o, fc2_w, fc2_b, out);
    loss_kernel<<<1, 64, 0, stream>>>(out, out);
}

// Round 9
// 466.702 us; speedup vs baseline: 1.2302x; 1.2302x over previous
//
#include <hip/hip_runtime.h>
#include <hip/hip_bf16.h>
#include <math.h>

#define EPS 1e-5f

// ---------------------------------------------------------------------------
// conv0-style K=4,S=2,P=1 conv: 2 px/thread, 8 couts/thread, aligned float4
// row loads from global (L2-resident), weights in LDS. No input LDS tile —
// R8 showed tile staging (non-pow2 div/mod addressing + barriers + LDS
// occupancy cap) costs more than L2-hit loads.
// Requires OW even, NPX/2 divisible by TPB.
// ---------------------------------------------------------------------------
template<int CIN, int COUT, int H, int W, int TPB>
__global__ __launch_bounds__(TPB) void conv42V(const float* __restrict__ in,
                                               const float* __restrict__ w,
                                               const float* __restrict__ bias,
                                               float* __restrict__ out, int relu)
{
    constexpr int OH  = H / 2, OW = W / 2;
    constexpr int NPX = OH * OW;
    constexpr int PXB = (NPX / 2) / TPB;
    constexpr int NCG = COUT / 8;

    __shared__ float sW[CIN * 8 * 16];   // [ci][co][16]
    __shared__ float sB[8];

    int t   = threadIdx.x;
    int bx  = blockIdx.x;
    int pxb = bx % PXB;
    int cg  = (bx / PXB) % NCG;
    int n   = bx / (PXB * NCG);

    for (int i = t; i < CIN * 128; i += TPB) {
        int ci = i >> 7;
        int r  = i & 127;
        int co = r >> 4;
        int k  = r & 15;
        sW[i] = w[((size_t)(cg * 8 + co) * CIN + ci) * 16 + k];
    }
    if (t < 8) sB[t] = bias[cg * 8 + t];
    __syncthreads();

    int px0 = (pxb * TPB + t) * 2;
    int oh  = px0 / OW;
    int ow0 = px0 % OW;            // even
    int ih0 = oh * 2 - 1;
    int iwq = ow0 * 2;             // multiple of 4

    float acc[8][2];
#pragma unroll
    for (int j = 0; j < 8; ++j) { acc[j][0] = sB[j]; acc[j][1] = sB[j]; }

    const float* ib = in + (size_t)n * CIN * H * W;
#pragma unroll 1
    for (int ci = 0; ci < CIN; ++ci) {
        const float* plane = ib + (size_t)ci * H * W;
#pragma unroll
        for (int kh = 0; kh < 4; ++kh) {
            int ih = ih0 + kh;
            float p[6];
            if ((unsigned)ih < (unsigned)H) {
                const float* row = plane + (size_t)ih * W;
                float4 q = *(const float4*)(row + iwq);
                p[1] = q.x; p[2] = q.y; p[3] = q.z; p[4] = q.w;
                p[0] = (iwq >= 1)     ? row[iwq - 1] : 0.f;
                p[5] = (iwq + 4 < W)  ? row[iwq + 4] : 0.f;
            } else {
#pragma unroll
                for (int k2 = 0; k2 < 6; ++k2) p[k2] = 0.f;
            }
#pragma unroll
            for (int j = 0; j < 8; ++j) {
                const float4 wv = *(const float4*)(sW + (ci * 8 + j) * 16 + kh * 4);
                acc[j][0] = fmaf(p[0], wv.x, acc[j][0]);
                acc[j][0] = fmaf(p[1], wv.y, acc[j][0]);
                acc[j][0] = fmaf(p[2], wv.z, acc[j][0]);
                acc[j][0] = fmaf(p[3], wv.w, acc[j][0]);
                acc[j][1] = fmaf(p[2], wv.x, acc[j][1]);
                acc[j][1] = fmaf(p[3], wv.y, acc[j][1]);
                acc[j][1] = fmaf(p[4], wv.z, acc[j][1]);
                acc[j][1] = fmaf(p[5], wv.w, acc[j][1]);
            }
        }
    }
    float* ob = out + ((size_t)(n * COUT + cg * 8) * NPX) + px0;
#pragma unroll
    for (int j = 0; j < 8; ++j) {
        float2 v;
        v.x = acc[j][0];
        v.y = acc[j][1];
        if (relu) { v.x = fmaxf(v.x, 0.f); v.y = fmaxf(v.y, 0.f); }
        *(float2*)(ob + (size_t)j * NPX) = v;
    }
}

// ---------------------------------------------------------------------------
// L0: (5,256,192)->(8,128,96), +bias +ReLU. grid 1536, block 256.
// ci loop MUST stay unroll 1 (R6: full unroll -> VGPR 256 spill).
// ---------------------------------------------------------------------------
__global__ __launch_bounds__(256) void conv0(const float* __restrict__ in,
                                             const float* __restrict__ w,
                                             const float* __restrict__ bias,
                                             float* __restrict__ out)
{
    __shared__ float sW[5 * 8 * 16];   // [ci][co][16]
    __shared__ float sB[8];
    int t   = threadIdx.x;
    int n   = blockIdx.x / 24;
    int pxb = blockIdx.x % 24;
    for (int i = t; i < 640; i += 256) {
        int ci = i / 128;
        int r  = i % 128;
        int co = r / 16;
        int k  = r % 16;
        sW[i] = w[((size_t)co * 5 + ci) * 16 + k];
    }
    if (t < 8) sB[t] = bias[t];
    __syncthreads();

    int px0 = (pxb * 256 + t) * 2;
    int oh  = px0 / 96;
    int ow0 = px0 % 96;            // even
    int ih0 = oh * 2 - 1;
    int iwq = ow0 * 2;             // multiple of 4

    float acc[8][2];
#pragma unroll
    for (int j = 0; j < 8; ++j) { acc[j][0] = sB[j]; acc[j][1] = sB[j]; }

    const float* ib = in + (size_t)n * 5 * 256 * 192;
#pragma unroll 1
    for (int ci = 0; ci < 5; ++ci) {
        const float* plane = ib + (size_t)ci * 256 * 192;
#pragma unroll
        for (int kh = 0; kh < 4; ++kh) {
            int ih = ih0 + kh;
            float p[6];
            if ((unsigned)ih < 256u) {
                const float* row = plane + (size_t)ih * 192;
                float4 q = *(const float4*)(row + iwq);
                p[1] = q.x; p[2] = q.y; p[3] = q.z; p[4] = q.w;
                p[0] = (iwq >= 1)      ? row[iwq - 1] : 0.f;
                p[5] = (iwq + 4 < 192) ? row[iwq + 4] : 0.f;
            } else {
#pragma unroll
                for (int k2 = 0; k2 < 6; ++k2) p[k2] = 0.f;
            }
#pragma unroll
            for (int j = 0; j < 8; ++j) {
                const float4 wv = *(const float4*)(sW + (ci * 8 + j) * 16 + kh * 4);
                acc[j][0] = fmaf(p[0], wv.x, acc[j][0]);
                acc[j][0] = fmaf(p[1], wv.y, acc[j][0]);
                acc[j][0] = fmaf(p[2], wv.z, acc[j][0]);
                acc[j][0] = fmaf(p[3], wv.w, acc[j][0]);
                acc[j][1] = fmaf(p[2], wv.x, acc[j][1]);
                acc[j][1] = fmaf(p[3], wv.y, acc[j][1]);
                acc[j][1] = fmaf(p[4], wv.z, acc[j][1]);
                acc[j][1] = fmaf(p[5], wv.w, acc[j][1]);
            }
        }
    }
    float* ob = out + (size_t)n * 8 * 12288 + px0;
#pragma unroll
    for (int j = 0; j < 8; ++j) {
        float2 v;
        v.x = fmaxf(acc[j][0], 0.f);
        v.y = fmaxf(acc[j][1], 0.f);
        *(float2*)(ob + (size_t)j * 12288) = v;
    }
}

// ---------------------------------------------------------------------------
// L3: (32,32,24)->(64,16,12), ci-split 4 chunks of 8, CPT=8, zero-padded
// full-plane LDS tile. grid 2048 x 192. Partials, no bias.
// ---------------------------------------------------------------------------
__global__ __launch_bounds__(192) void conv_l3s(const float* __restrict__ in,
                                                const float* __restrict__ w,
                                                float* __restrict__ pbuf)
{
    __shared__ float sT[8 * 34 * 26];  // padded planes
    __shared__ float sW[8 * 8 * 16];   // [ci][j][16]
    int t  = threadIdx.x;
    int b  = blockIdx.x;
    int cg = b & 7;
    int s  = (b >> 3) & 3;
    int n  = b >> 5;

    const float* ib = in + ((size_t)n * 32 + s * 8) * 768;
    for (int i = t; i < 8 * 884; i += 192) {
        int ci  = i / 884;
        int r   = i % 884;
        int ihp = r / 26;
        int iwp = r % 26;
        int ih  = ihp - 1;
        int iw  = iwp - 1;
        float v = 0.f;
        if ((unsigned)ih < 32u && (unsigned)iw < 24u)
            v = ib[ci * 768 + ih * 24 + iw];
        sT[i] = v;
    }
    for (int i = t; i < 1024; i += 192) {
        int ci = i >> 7;
        int r  = i & 127;
        int j  = r >> 4;
        int k  = r & 15;
        sW[i] = w[((size_t)(cg * 8 + j) * 32 + s * 8 + ci) * 16 + k];
    }
    __syncthreads();

    int oh = t / 12, ow = t % 12;
    float acc[8];
#pragma unroll
    for (int j = 0; j < 8; ++j) acc[j] = 0.f;

#pragma unroll 1
    for (int ci = 0; ci < 8; ++ci) {
        const float* tp = sT + ci * 884 + (2 * oh) * 26 + 2 * ow;
        float p[16];
#pragma unroll
        for (int kh = 0; kh < 4; ++kh)
#pragma unroll
            for (int kw = 0; kw < 4; ++kw)
                p[kh * 4 + kw] = tp[kh * 26 + kw];
        const float* wp = sW + ci * 128;
#pragma unroll
        for (int j = 0; j < 8; ++j) {
#pragma unroll
            for (int k = 0; k < 16; ++k)
                acc[j] = fmaf(p[k], wp[j * 16 + k], acc[j]);
        }
    }
    float* pb = pbuf + (((size_t)s * 64 + n) * 64 + cg * 8) * 192 + t;
#pragma unroll
    for (int j = 0; j < 8; ++j) pb[j * 192] = acc[j];
}

// ---------------------------------------------------------------------------
// L3 reduce: sum 4 splits + instance norm over 192 px + relu, write
// TRANSPOSED [co][px][n] for conv_l4. wave per (n,co). grid 1024, block 256.
// ---------------------------------------------------------------------------
__global__ __launch_bounds__(256) void reduce_norm_l3T(const float* __restrict__ pbuf,
                                                       float* __restrict__ dst_t)
{
    int gid  = blockIdx.x * blockDim.x + threadIdx.x;
    int wv   = gid >> 6;          // 0..4095 = n*64+co
    int lane = gid & 63;
    int n  = wv >> 6;
    int co = wv & 63;
    float tv[3];
#pragma unroll
    for (int k = 0; k < 3; ++k) {
        int i = lane + k * 64;
        float sum = 0.f;
#pragma unroll
        for (int s = 0; s < 4; ++s)
            sum += pbuf[((size_t)s * 4096 + wv) * 192 + i];
        tv[k] = sum;
    }
    float s1 = tv[0] + tv[1] + tv[2];
    float s2 = tv[0]*tv[0] + tv[1]*tv[1] + tv[2]*tv[2];
    for (int m = 32; m >= 1; m >>= 1) {
        s1 += __shfl_xor(s1, m);
        s2 += __shfl_xor(s2, m);
    }
    float mean = s1 * (1.f / 192.f);
    float var  = s2 * (1.f / 192.f) - mean * mean;
    float r = rsqrtf(var + EPS);
#pragma unroll
    for (int k = 0; k < 3; ++k) {
        int i = lane + k * 64;
        float y = fmaxf((tv[k] - mean) * r, 0.f);
        dst_t[((size_t)co * 192 + i) * 64 + n] = y;
    }
}

// ---------------------------------------------------------------------------
// Single-pass instance norm: register-cached float4. HW = TPB*VPT*4. In place.
// ---------------------------------------------------------------------------
template<int TPB, int VPT>
__global__ void inorm_blockv(float* __restrict__ data, int relu)
{
    const int HW = TPB * VPT * 4;
    float4* p = (float4*)(data + (size_t)blockIdx.x * HW);
    float4 v[VPT];
    float s = 0.f, q = 0.f;
#pragma unroll
    for (int k = 0; k < VPT; ++k) {
        v[k] = p[threadIdx.x + k * TPB];
        s += v[k].x + v[k].y + v[k].z + v[k].w;
        q += v[k].x*v[k].x + v[k].y*v[k].y + v[k].z*v[k].z + v[k].w*v[k].w;
    }
    for (int m2 = 32; m2 >= 1; m2 >>= 1) {
        s += __shfl_xor(s, m2);
        q += __shfl_xor(q, m2);
    }
    __shared__ float ss[TPB / 64], sq[TPB / 64], sm[2];
    int wave = threadIdx.x >> 6, lane = threadIdx.x & 63;
    if (lane == 0) { ss[wave] = s; sq[wave] = q; }
    __syncthreads();
    if (threadIdx.x == 0) {
        float a = 0.f, b2 = 0.f;
#pragma unroll
        for (int k = 0; k < TPB / 64; ++k) { a += ss[k]; b2 += sq[k]; }
        float mm = a / (float)HW;
        float vv = b2 / (float)HW - mm * mm;
        sm[0] = mm; sm[1] = rsqrtf(vv + EPS);
    }
    __syncthreads();
    float m = sm[0], r = sm[1];
#pragma unroll
    for (int k = 0; k < VPT; ++k) {
        float4 y;
        y.x = (v[k].x - m) * r; y.y = (v[k].y - m) * r;
        y.z = (v[k].z - m) * r; y.w = (v[k].w - m) * r;
        if (relu) {
            y.x = fmaxf(y.x, 0.f); y.y = fmaxf(y.y, 0.f);
            y.z = fmaxf(y.z, 0.f); y.w = fmaxf(y.w, 0.f);
        }
        p[threadIdx.x + k * TPB] = y;
    }
}

// ---------------------------------------------------------------------------
// L4: (64,16,12)->(128,8,6). Input transposed [ci][px(192)][n(64)].
// ---------------------------------------------------------------------------
__global__ __launch_bounds__(256) void conv_l4(const float* __restrict__ in_t,
                                               const float* __restrict__ w,
                                               float* __restrict__ pbuf)
{
    int t    = threadIdx.x;
    int lane = t & 63;                      // = n
    int gw   = __builtin_amdgcn_readfirstlane(blockIdx.x * 4 + (t >> 6)); // 0..1023
    int cog  = gw & 63;
    int cic  = (gw >> 6) & 7;
    int half = gw >> 9;
    int cc   = cic * 8;
    int co0  = cog * 2;
    int oh0  = half * 4;

    float acc[2][24];
#pragma unroll
    for (int j = 0; j < 2; ++j)
#pragma unroll
        for (int p = 0; p < 24; ++p) acc[j][p] = 0.f;

    const float* wp = w + ((size_t)co0 * 64 + cc) * 16;

#pragma unroll 1
    for (int ci = 0; ci < 8; ++ci) {
        const float* pl = in_t + (size_t)(cc + ci) * 192 * 64 + lane;
        float wr[2][16];
#pragma unroll
        for (int k = 0; k < 16; ++k) {
            wr[0][k] = wp[(0 * 64 + ci) * 16 + k];
            wr[1][k] = wp[(1 * 64 + ci) * 16 + k];
        }
#pragma unroll
        for (int kh = 0; kh < 4; ++kh) {
            float p[4][12];
#pragma unroll
            for (int o = 0; o < 4; ++o) {
                int ih = 2 * (oh0 + o) - 1 + kh;
                if ((unsigned)ih < 16u) {
#pragma unroll
                    for (int c = 0; c < 12; ++c)
                        p[o][c] = pl[(size_t)(ih * 12 + c) * 64];
                } else {
#pragma unroll
                    for (int c = 0; c < 12; ++c) p[o][c] = 0.f;
                }
            }
#pragma unroll
            for (int o = 0; o < 4; ++o)
#pragma unroll
                for (int ow = 0; ow < 6; ++ow) {
#pragma unroll
                    for (int kw = 0; kw < 4; ++kw) {
                        int iw = 2 * ow - 1 + kw;
                        if (iw < 0 || iw >= 12) continue;
                        float pv = p[o][iw];
                        acc[0][o * 6 + ow] = fmaf(pv, wr[0][kh * 4 + kw], acc[0][o * 6 + ow]);
                        acc[1][o * 6 + ow] = fmaf(pv, wr[1][kh * 4 + kw], acc[1][o * 6 + ow]);
                    }
                }
        }
    }

    float* pb = pbuf + ((size_t)(cic * 64 + lane) * 128 + co0) * 48 + oh0 * 6;
#pragma unroll
    for (int j = 0; j < 2; ++j) {
        float4* o4 = (float4*)(pb + j * 48);
#pragma unroll
        for (int q = 0; q < 6; ++q)
            o4[q] = make_float4(acc[j][q * 4 + 0], acc[j][q * 4 + 1],
                                acc[j][q * 4 + 2], acc[j][q * 4 + 3]);
    }
}

__global__ __launch_bounds__(256) void reduce_norm48(const float* __restrict__ pbuf,
                                                     float* __restrict__ out)
{
    int g  = blockIdx.x * blockDim.x + threadIdx.x;   // 8192 threads
    int co = g & 127;
    int n  = g >> 7;
    float s[48];
#pragma unroll
    for (int p = 0; p < 48; ++p) s[p] = 0.f;
#pragma unroll 1
    for (int c = 0; c < 8; ++c) {
        const float4* p4 = (const float4*)(pbuf + ((size_t)(c * 64 + n) * 128 + co) * 48);
#pragma unroll
        for (int q = 0; q < 12; ++q) {
            float4 a = p4[q];
            s[q * 4 + 0] += a.x; s[q * 4 + 1] += a.y;
            s[q * 4 + 2] += a.z; s[q * 4 + 3] += a.w;
        }
    }
    float m = 0.f;
#pragma unroll
    for (int p = 0; p < 48; ++p) m += s[p];
    m *= (1.f / 48.f);
    float q = 0.f;
#pragma unroll
    for (int p = 0; p < 48; ++p) { float d = s[p] - m; q += d * d; }
    q *= (1.f / 48.f);
    float r = rsqrtf(q + EPS);
    float4* o4 = (float4*)(out + ((size_t)n * 128 + co) * 48);
#pragma unroll
    for (int qq = 0; qq < 12; ++qq) {
        float4 v;
        v.x = fmaxf((s[qq * 4 + 0] - m) * r, 0.f);
        v.y = fmaxf((s[qq * 4 + 1] - m) * r, 0.f);
        v.z = fmaxf((s[qq * 4 + 2] - m) * r, 0.f);
        v.w = fmaxf((s[qq * 4 + 3] - m) * r, 0.f);
        o4[qq] = v;
    }
}

// ---------------------------------------------------------------------------
// L6/L7: (256,4,3)->(256,4,3), K=3,S=1,P=1. lane=n scheme.
// ---------------------------------------------------------------------------
__global__ __launch_bounds__(256) void conv_l67(const float* __restrict__ in,
                                                const float* __restrict__ w,
                                                float* __restrict__ pbuf)
{
    int t    = threadIdx.x;
    int gw   = __builtin_amdgcn_readfirstlane(blockIdx.x * 4 + (t >> 6));
    int lane = t & 63;
    int cic  = gw >> 6;
    int cog  = gw & 63;
    int cc   = cic * 16;
    int co0  = cog * 4;

    float acc[4][12];
#pragma unroll
    for (int j = 0; j < 4; ++j)
#pragma unroll
        for (int p = 0; p < 12; ++p) acc[j][p] = 0.f;

    const float* ip = in + ((size_t)lane * 256 + cc) * 12;
    const float* wp = w + ((size_t)co0 * 256 + cc) * 9;

#pragma unroll 2
    for (int ci = 0; ci < 16; ++ci) {
        float p[12];
        const float4* p4 = (const float4*)(ip + ci * 12);
        float4 a0 = p4[0], a1 = p4[1], a2 = p4[2];
        p[0] = a0.x; p[1] = a0.y; p[2]  = a0.z; p[3]  = a0.w;
        p[4] = a1.x; p[5] = a1.y; p[6]  = a1.z; p[7]  = a1.w;
        p[8] = a2.x; p[9] = a2.y; p[10] = a2.z; p[11] = a2.w;
#pragma unroll
        for (int j = 0; j < 4; ++j) {
            const float* wj = wp + ((size_t)j * 256 + ci) * 9;
            float wr[9];
#pragma unroll
            for (int k = 0; k < 9; ++k) wr[k] = wj[k];
#pragma unroll
            for (int oh = 0; oh < 4; ++oh)
#pragma unroll
                for (int ow = 0; ow < 3; ++ow)
#pragma unroll
                    for (int kh = 0; kh < 3; ++kh) {
                        int ih = oh - 1 + kh;
                        if (ih < 0 || ih >= 4) continue;
#pragma unroll
                        for (int kw = 0; kw < 3; ++kw) {
                            int iw = ow - 1 + kw;
                            if (iw < 0 || iw >= 3) continue;
                            acc[j][oh * 3 + ow] =
                                fmaf(p[ih * 3 + iw], wr[kh * 3 + kw], acc[j][oh * 3 + ow]);
                        }
                    }
        }
    }

    float* pb = pbuf + ((size_t)(cic * 64 + lane) * 256 + co0) * 12;
#pragma unroll
    for (int j = 0; j < 4; ++j) {
        float4* o4 = (float4*)(pb + j * 12);
        o4[0] = make_float4(acc[j][0], acc[j][1], acc[j][2],  acc[j][3]);
        o4[1] = make_float4(acc[j][4], acc[j][5], acc[j][6],  acc[j][7]);
        o4[2] = make_float4(acc[j][8], acc[j][9], acc[j][10], acc[j][11]);
    }
}

// ---------------------------------------------------------------------------
// L5: (128,8,6)->(256,4,3), K=4,S=2,P=1. lane=n scheme.
// ---------------------------------------------------------------------------
__global__ __launch_bounds__(256) void conv_l5(const float* __restrict__ in,
                                               const float* __restrict__ w,
                                               float* __restrict__ pbuf)
{
    int t    = threadIdx.x;
    int gw   = __builtin_amdgcn_readfirstlane(blockIdx.x * 4 + (t >> 6));
    int lane = t & 63;
    int cic  = gw >> 6;
    int cog  = gw & 63;
    int cc   = cic * 8;
    int co0  = cog * 4;

    float acc[4][12];
#pragma unroll
    for (int j = 0; j < 4; ++j)
#pragma unroll
        for (int p = 0; p < 12; ++p) acc[j][p] = 0.f;

    const float* ip = in + ((size_t)lane * 128 + cc) * 48;
    const float* wp = w + ((size_t)co0 * 128 + cc) * 16;

#pragma unroll 1
    for (int ci = 0; ci < 8; ++ci) {
        float p[48];
        const float4* p4 = (const float4*)(ip + ci * 48);
#pragma unroll
        for (int q = 0; q < 12; ++q) {
            float4 a = p4[q];
            p[q * 4 + 0] = a.x; p[q * 4 + 1] = a.y; p[q * 4 + 2] = a.z; p[q * 4 + 3] = a.w;
        }
#pragma unroll
        for (int j = 0; j < 4; ++j) {
            const float* wj = wp + ((size_t)j * 128 + ci) * 16;
            float wr[16];
#pragma unroll
            for (int k = 0; k < 16; ++k) wr[k] = wj[k];
#pragma unroll
            for (int oh = 0; oh < 4; ++oh)
#pragma unroll
                for (int ow = 0; ow < 3; ++ow) {
                    int ih0 = 2 * oh - 1, iw0 = 2 * ow - 1;
#pragma unroll
                    for (int kh = 0; kh < 4; ++kh) {
                        int ih = ih0 + kh;
                        if (ih < 0 || ih >= 8) continue;
#pragma unroll
                        for (int kw = 0; kw < 4; ++kw) {
                            int iw = iw0 + kw;
                            if (iw < 0 || iw >= 6) continue;
                            acc[j][oh * 3 + ow] =
                                fmaf(p[ih * 6 + iw], wr[kh * 4 + kw], acc[j][oh * 3 + ow]);
                        }
                    }
                }
        }
    }

    float* pb = pbuf + ((size_t)(cic * 64 + lane) * 256 + co0) * 12;
#pragma unroll
    for (int j = 0; j < 4; ++j) {
        float4* o4 = (float4*)(pb + j * 12);
        o4[0] = make_float4(acc[j][0], acc[j][1], acc[j][2],  acc[j][3]);
        o4[1] = make_float4(acc[j][4], acc[j][5], acc[j][6],  acc[j][7]);
        o4[2] = make_float4(acc[j][8], acc[j][9], acc[j][10], acc[j][11]);
    }
}

__global__ __launch_bounds__(256) void reduce_norm12(const float* __restrict__ pbuf,
                                                     float* __restrict__ out)
{
    int g  = blockIdx.x * blockDim.x + threadIdx.x;   // 16384 threads
    int co = g & 255;
    int n  = g >> 8;
    float s[12];
#pragma unroll
    for (int p = 0; p < 12; ++p) s[p] = 0.f;
#pragma unroll 1
    for (int c = 0; c < 16; ++c) {
        const float4* p4 = (const float4*)(pbuf + ((size_t)(c * 64 + n) * 256 + co) * 12);
        float4 a = p4[0], b = p4[1], d = p4[2];
        s[0] += a.x; s[1] += a.y; s[2]  += a.z; s[3]  += a.w;
        s[4] += b.x; s[5] += b.y; s[6]  += b.z; s[7]  += b.w;
        s[8] += d.x; s[9] += d.y; s[10] += d.z; s[11] += d.w;
    }
    float m = 0.f;
#pragma unroll
    for (int p = 0; p < 12; ++p) m += s[p];
    m *= (1.f / 12.f);
    float q = 0.f;
#pragma unroll
    for (int p = 0; p < 12; ++p) { float d = s[p] - m; q += d * d; }
    q *= (1.f / 12.f);
    float r = rsqrtf(q + EPS);
    float* op = out + ((size_t)n * 256 + co) * 12;
    float4* o4 = (float4*)op;
    float y[12];
#pragma unroll
    for (int p = 0; p < 12; ++p) y[p] = fmaxf((s[p] - m) * r, 0.f);
    o4[0] = make_float4(y[0], y[1], y[2],  y[3]);
    o4[1] = make_float4(y[4], y[5], y[6],  y[7]);
    o4[2] = make_float4(y[8], y[9], y[10], y[11]);
}

// maxpool (64,256,4,3) -> (64,512)
__global__ void pool_kernel(const float* __restrict__ in, float* __restrict__ out)
{
    int idx = blockIdx.x * blockDim.x + threadIdx.x;
    if (idx >= 64 * 512) return;
    int f = idx & 511;
    int n = idx >> 9;
    int c = f >> 1;
    int h = f & 1;
    const float* p = in + (((size_t)n * 256 + c) * 4 + h * 2) * 3;
    out[idx] = fmaxf(fmaxf(p[0], p[1]), fmaxf(p[3], p[4]));
}

__global__ void fc1_kernel(const float* __restrict__ in, const float* __restrict__ w,
                           const float* __restrict__ b, float* __restrict__ out)
{
    int idx = blockIdx.x * blockDim.x + threadIdx.x;
    if (idx >= 64 * 128) return;
    int j = idx & 127;
    int n = idx >> 7;
    const float* x  = in + n * 512;
    const float* wr = w + j * 512;
    float acc = b[j];
    for (int f = 0; f < 512; ++f) acc = fmaf(x[f], wr[f], acc);
    out[idx] = fmaxf(acc, 0.f);
}

__global__ void fc2_kernel(const float* __restrict__ in, const float* __restrict__ w,
                           const float* __restrict__ b, float* __restrict__ out)
{
    int idx = blockIdx.x * blockDim.x + threadIdx.x;
    if (idx >= 64 * 50) return;
    int k = idx % 50;
    int n = idx / 50;
    const float* x  = in + n * 128;
    const float* wr = w + k * 128;
    float acc = b[k];
    for (int f = 0; f < 128; ++f) acc = fmaf(x[f], wr[f], acc);
    out[idx] = tanhf(acc);
}

__global__ void loss_kernel(const float* __restrict__ pts, float* __restrict__ out)
{
    __shared__ float acc[4][64];
    int n = threadIdx.x;
    float rx = 0.f, ry = 0.f, cx = 0.f, cy = 0.f;
    {
        const float* g = pts + n * 50;
        for (int r = 0; r < 5; ++r)
            for (int j = 0; j < 3; ++j)
                for (int d = 0; d < 2; ++d) {
                    float a0 = g[(r * 5 + j) * 2 + d];
                    float a1 = g[(r * 5 + j + 1) * 2 + d];
                    float a2 = g[(r * 5 + j + 2) * 2 + d];
                    float d0 = (a1 - a0) * (a1 - a0);
                    float d1 = (a2 - a1) * (a2 - a1);
                    float t = fmaxf(0.08f, fabsf(d1 - d0));
                    if (d == 0) rx += t; else ry += t;
                }
        for (int r = 0; r < 5; ++r)
            for (int j = 0; j < 3; ++j)
                for (int d = 0; d < 2; ++d) {
                    float a0 = g[(j * 5 + r) * 2 + d];
                    float a1 = g[((j + 1) * 5 + r) * 2 + d];
                    float a2 = g[((j + 2) * 5 + r) * 2 + d];
                    float d0 = (a1 - a0) * (a1 - a0);
                    float d1 = (a2 - a1) * (a2 - a1);
                    float t = fmaxf(0.08f, fabsf(d1 - d0));
                    if (d == 0) cx += t; else cy += t;
                }
    }
    acc[0][n] = rx; acc[1][n] = ry; acc[2][n] = cx; acc[3][n] = cy;
    __syncthreads();
    if (n == 0) {
        float s0 = 0.f, s1 = 0.f, s2 = 0.f, s3 = 0.f;
        for (int i = 0; i < 64; ++i) {
            s0 += acc[0][i]; s1 += acc[1][i]; s2 += acc[2][i]; s3 += acc[3][i];
        }
        float inv = 1.0f / (64.0f * 15.0f);
        out[3200] = s0 * inv;
        out[3201] = s1 * inv;
        out[3202] = s2 * inv;
        out[3203] = s3 * inv;
        const float* g = pts;
        float rg = 0.f, cg = 0.f;
        for (int r = 0; r < 5; ++r)
            for (int j = 0; j < 3; ++j) {
                float x0 = g[(r * 5 + j) * 2],     y0 = g[(r * 5 + j) * 2 + 1];
                float x1 = g[(r * 5 + j + 1) * 2], y1 = g[(r * 5 + j + 1) * 2 + 1];
                float x2 = g[(r * 5 + j + 2) * 2], y2 = g[(r * 5 + j + 2) * 2 + 1];
                rg += fabsf((y1 - y0) * (x1 - x2) - (y1 - y2) * (x1 - x0));
            }
        for (int r = 0; r < 5; ++r)
            for (int j = 0; j < 3; ++j) {
                float x0 = g[(j * 5 + r) * 2],       y0 = g[(j * 5 + r) * 2 + 1];
                float x1 = g[((j + 1) * 5 + r) * 2], y1 = g[((j + 1) * 5 + r) * 2 + 1];
                float x2 = g[((j + 2) * 5 + r) * 2], y2 = g[((j + 2) * 5 + r) * 2 + 1];
                cg += fabsf((y1 - y0) * (x1 - x2) - (y1 - y2) * (x1 - x0));
            }
        out[3204] = fmaxf(rg, 0.02f);
        out[3205] = fmaxf(cg, 0.02f);
    }
}

extern "C" void kernel_launch(void* const* d_in, const int* in_sizes, int n_in,
                              void* d_out, int out_size, void* d_ws, size_t ws_size,
                              hipStream_t stream)
{
    const float* x = (const float*)d_in[0];
    const float* w[8], *bia[8];
    for (int i = 0; i < 6; ++i) { w[i] = (const float*)d_in[1 + 2 * i]; bia[i] = (const float*)d_in[2 + 2 * i]; }
    w[6] = (const float*)d_in[13]; bia[6] = (const float*)d_in[14];
    w[7] = (const float*)d_in[15]; bia[7] = (const float*)d_in[16];
    const float* fc1_w = (const float*)d_in[17];
    const float* fc1_b = (const float*)d_in[18];
    const float* fc2_w = (const float*)d_in[19];
    const float* fc2_b = (const float*)d_in[20];
    float* out = (float*)d_out;

    // workspace (floats):
    float* A      = (float*)d_ws;              // [0 .. 6291456)
    float* Bf     = A + 6291456;               // [6291456 .. 9437184)
    float* pooled = Bf + 3145728;
    float* fc1o   = pooled + 32768;
    float* pbuf3  = A + 1572864;               // L3 partials, 3145728 floats (inside A)
    float* At     = A;                         // L3 norm'd transposed out, 786432 floats
    float* l4out  = A + 1048576;               // 393216 floats
    float* pbuf   = A + 3145728;               // L4-L7 partials, <=3145728 floats

    const int N = 64;

    // ---- L0: conv+bias+relu, then norm ----
    conv0<<<1536, 256, 0, stream>>>(x, w[0], bia[0], A);
    inorm_blockv<256, 12><<<N * 8, 256, 0, stream>>>(A, 0);           // HW=12288

    // ---- L1: (8,128,96)->(16,64,48), conv0-style ----
    conv42V<8, 16, 128, 96, 256><<<768, 256, 0, stream>>>(A, w[1], bia[1], Bf, 0);
    inorm_blockv<256, 3><<<N * 16, 256, 0, stream>>>(Bf, 1);          // HW=3072

    // ---- L2: (16,64,48)->(32,32,24), conv0-style; out -> A[0..1572864) ----
    conv42V<16, 32, 64, 48, 192><<<512, 192, 0, stream>>>(Bf, w[2], bia[2], A, 0);
    inorm_blockv<192, 1><<<N * 32, 192, 0, stream>>>(A, 1);           // HW=768

    // ---- L3: LDS-tiled ci-split conv + fused reduce/norm/relu, transposed out ----
    conv_l3s<<<2048, 192, 0, stream>>>(A, w[3], pbuf3);
    reduce_norm_l3T<<<1024, 256, 0, stream>>>(pbuf3, At);

    // ---- L4 ----
    conv_l4<<<256, 256, 0, stream>>>(At, w[4], pbuf);
    reduce_norm48<<<32, 256, 0, stream>>>(pbuf, l4out);

    // ---- L5 ----
    conv_l5<<<256, 256, 0, stream>>>(l4out, w[5], pbuf);
    reduce_norm12<<<64, 256, 0, stream>>>(pbuf, Bf);

    // ---- L6 ----
    conv_l67<<<256, 256, 0, stream>>>(Bf, w[6], pbuf);
    reduce_norm12<<<64, 256, 0, stream>>>(pbuf, A);

    // ---- L7 ----
    conv_l67<<<256, 256, 0, stream>>>(A, w[7], pbuf);
    float* l7out = Bf + 262144;
    reduce_norm12<<<64, 256, 0, stream>>>(pbuf, l7out);

    pool_kernel<<<(64 * 512 + 255) / 256, 256, 0, stream>>>(l7out, pooled);
    fc1_kernel<<<(64 * 128 + 255) / 256, 256, 0, stream>>>(pooled, fc1_w, fc1_b, fc1o);
    fc2_kernel<<<(64 * 50 + 255) / 256, 256, 0, stream>>>(fc1o, fc2_w, fc2_b, out);
    loss_kernel<<<1, 64, 0, stream>>>(out, out);
}

// Round 10
// 423.264 us; speedup vs baseline: 1.3565x; 1.1026x over previous
//
#include <hip/hip_runtime.h>
#include <hip/hip_bf16.h>
#include <math.h>

#define EPS 1e-5f

// ---------------------------------------------------------------------------
// conv0-style K=4,S=2,P=1 conv: 2 px/thread, 8 couts/thread, aligned float4
// row loads from global (L2-resident), weights in LDS. (L1, L2)
// ---------------------------------------------------------------------------
template<int CIN, int COUT, int H, int W, int TPB>
__global__ __launch_bounds__(TPB) void conv42V(const float* __restrict__ in,
                                               const float* __restrict__ w,
                                               const float* __restrict__ bias,
                                               float* __restrict__ out, int relu)
{
    constexpr int OH  = H / 2, OW = W / 2;
    constexpr int NPX = OH * OW;
    constexpr int PXB = (NPX / 2) / TPB;
    constexpr int NCG = COUT / 8;

    __shared__ float sW[CIN * 8 * 16];   // [ci][co][16]
    __shared__ float sB[8];

    int t   = threadIdx.x;
    int bx  = blockIdx.x;
    int pxb = bx % PXB;
    int cg  = (bx / PXB) % NCG;
    int n   = bx / (PXB * NCG);

    for (int i = t; i < CIN * 128; i += TPB) {
        int ci = i >> 7;
        int r  = i & 127;
        int co = r >> 4;
        int k  = r & 15;
        sW[i] = w[((size_t)(cg * 8 + co) * CIN + ci) * 16 + k];
    }
    if (t < 8) sB[t] = bias[cg * 8 + t];
    __syncthreads();

    int px0 = (pxb * TPB + t) * 2;
    int oh  = px0 / OW;
    int ow0 = px0 % OW;            // even
    int ih0 = oh * 2 - 1;
    int iwq = ow0 * 2;             // multiple of 4

    float acc[8][2];
#pragma unroll
    for (int j = 0; j < 8; ++j) { acc[j][0] = sB[j]; acc[j][1] = sB[j]; }

    const float* ib = in + (size_t)n * CIN * H * W;
#pragma unroll 1
    for (int ci = 0; ci < CIN; ++ci) {
        const float* plane = ib + (size_t)ci * H * W;
#pragma unroll
        for (int kh = 0; kh < 4; ++kh) {
            int ih = ih0 + kh;
            float p[6];
            if ((unsigned)ih < (unsigned)H) {
                const float* row = plane + (size_t)ih * W;
                float4 q = *(const float4*)(row + iwq);
                p[1] = q.x; p[2] = q.y; p[3] = q.z; p[4] = q.w;
                p[0] = (iwq >= 1)     ? row[iwq - 1] : 0.f;
                p[5] = (iwq + 4 < W)  ? row[iwq + 4] : 0.f;
            } else {
#pragma unroll
                for (int k2 = 0; k2 < 6; ++k2) p[k2] = 0.f;
            }
#pragma unroll
            for (int j = 0; j < 8; ++j) {
                const float4 wv = *(const float4*)(sW + (ci * 8 + j) * 16 + kh * 4);
                acc[j][0] = fmaf(p[0], wv.x, acc[j][0]);
                acc[j][0] = fmaf(p[1], wv.y, acc[j][0]);
                acc[j][0] = fmaf(p[2], wv.z, acc[j][0]);
                acc[j][0] = fmaf(p[3], wv.w, acc[j][0]);
                acc[j][1] = fmaf(p[2], wv.x, acc[j][1]);
                acc[j][1] = fmaf(p[3], wv.y, acc[j][1]);
                acc[j][1] = fmaf(p[4], wv.z, acc[j][1]);
                acc[j][1] = fmaf(p[5], wv.w, acc[j][1]);
            }
        }
    }
    float* ob = out + ((size_t)(n * COUT + cg * 8) * NPX) + px0;
#pragma unroll
    for (int j = 0; j < 8; ++j) {
        float2 v;
        v.x = acc[j][0];
        v.y = acc[j][1];
        if (relu) { v.x = fmaxf(v.x, 0.f); v.y = fmaxf(v.y, 0.f); }
        *(float2*)(ob + (size_t)j * NPX) = v;
    }
}

// ---------------------------------------------------------------------------
// L0: (5,256,192)->(8,128,96), +bias +ReLU. grid 1536, block 256.
// ci loop MUST stay unroll 1 (R6: full unroll -> VGPR 256 spill).
// ---------------------------------------------------------------------------
__global__ __launch_bounds__(256) void conv0(const float* __restrict__ in,
                                             const float* __restrict__ w,
                                             const float* __restrict__ bias,
                                             float* __restrict__ out)
{
    __shared__ float sW[5 * 8 * 16];   // [ci][co][16]
    __shared__ float sB[8];
    int t   = threadIdx.x;
    int n   = blockIdx.x / 24;
    int pxb = blockIdx.x % 24;
    for (int i = t; i < 640; i += 256) {
        int ci = i / 128;
        int r  = i % 128;
        int co = r / 16;
        int k  = r % 16;
        sW[i] = w[((size_t)co * 5 + ci) * 16 + k];
    }
    if (t < 8) sB[t] = bias[t];
    __syncthreads();

    int px0 = (pxb * 256 + t) * 2;
    int oh  = px0 / 96;
    int ow0 = px0 % 96;            // even
    int ih0 = oh * 2 - 1;
    int iwq = ow0 * 2;             // multiple of 4

    float acc[8][2];
#pragma unroll
    for (int j = 0; j < 8; ++j) { acc[j][0] = sB[j]; acc[j][1] = sB[j]; }

    const float* ib = in + (size_t)n * 5 * 256 * 192;
#pragma unroll 1
    for (int ci = 0; ci < 5; ++ci) {
        const float* plane = ib + (size_t)ci * 256 * 192;
#pragma unroll
        for (int kh = 0; kh < 4; ++kh) {
            int ih = ih0 + kh;
            float p[6];
            if ((unsigned)ih < 256u) {
                const float* row = plane + (size_t)ih * 192;
                float4 q = *(const float4*)(row + iwq);
                p[1] = q.x; p[2] = q.y; p[3] = q.z; p[4] = q.w;
                p[0] = (iwq >= 1)      ? row[iwq - 1] : 0.f;
                p[5] = (iwq + 4 < 192) ? row[iwq + 4] : 0.f;
            } else {
#pragma unroll
                for (int k2 = 0; k2 < 6; ++k2) p[k2] = 0.f;
            }
#pragma unroll
            for (int j = 0; j < 8; ++j) {
                const float4 wv = *(const float4*)(sW + (ci * 8 + j) * 16 + kh * 4);
                acc[j][0] = fmaf(p[0], wv.x, acc[j][0]);
                acc[j][0] = fmaf(p[1], wv.y, acc[j][0]);
                acc[j][0] = fmaf(p[2], wv.z, acc[j][0]);
                acc[j][0] = fmaf(p[3], wv.w, acc[j][0]);
                acc[j][1] = fmaf(p[2], wv.x, acc[j][1]);
                acc[j][1] = fmaf(p[3], wv.y, acc[j][1]);
                acc[j][1] = fmaf(p[4], wv.z, acc[j][1]);
                acc[j][1] = fmaf(p[5], wv.w, acc[j][1]);
            }
        }
    }
    float* ob = out + (size_t)n * 8 * 12288 + px0;
#pragma unroll
    for (int j = 0; j < 8; ++j) {
        float2 v;
        v.x = fmaxf(acc[j][0], 0.f);
        v.y = fmaxf(acc[j][1], 0.f);
        *(float2*)(ob + (size_t)j * 12288) = v;
    }
}

// ---------------------------------------------------------------------------
// Instance norm for L2 output, writes TRANSPOSED [c][px][n] + relu.
// src [n][c][768]; wave per (n,c) plane; 12 elems/lane.
// ---------------------------------------------------------------------------
__global__ __launch_bounds__(256) void inorm_wave_T768(const float* __restrict__ src,
                                                       float* __restrict__ dst_t)
{
    int gid  = blockIdx.x * blockDim.x + threadIdx.x;
    int wv   = gid >> 6;          // 0..2047 = n*32+c
    int lane = gid & 63;
    int n = wv >> 5;
    int c = wv & 31;
    const float* p = src + (size_t)wv * 768;
    float tv[12];
    float s1 = 0.f, s2 = 0.f;
#pragma unroll
    for (int k = 0; k < 12; ++k) {
        float v = p[lane + k * 64];
        tv[k] = v;
        s1 += v; s2 += v * v;
    }
    for (int m = 32; m >= 1; m >>= 1) {
        s1 += __shfl_xor(s1, m);
        s2 += __shfl_xor(s2, m);
    }
    float mean = s1 * (1.f / 768.f);
    float var  = s2 * (1.f / 768.f) - mean * mean;
    float r = rsqrtf(var + EPS);
#pragma unroll
    for (int k = 0; k < 12; ++k) {
        int i = lane + k * 64;
        float y = fmaxf((tv[k] - mean) * r, 0.f);
        dst_t[((size_t)c * 768 + i) * 64 + n] = y;
    }
}

// ---------------------------------------------------------------------------
// L3: (32,32,24)->(64,16,12), lane=n scheme on transposed input [ci][px][n].
// wave = (co-pair(32) x ci-chunk(4 of 8) x out-row(16)) = 2048 waves.
// grid 512 x 256. Weights wave-uniform (SGPR). Partials to pbuf (4 splits,
// same layout as reduce_norm_l3T expects). No bias (cancels under norm).
// ---------------------------------------------------------------------------
__global__ __launch_bounds__(256) void conv_l3t(const float* __restrict__ in_t,
                                                const float* __restrict__ w,
                                                float* __restrict__ pbuf)
{
    int t    = threadIdx.x;
    int lane = t & 63;                       // = n
    int gw   = __builtin_amdgcn_readfirstlane(blockIdx.x * 4 + (t >> 6)); // 0..2047
    int cog  = gw & 31;
    int cic  = (gw >> 5) & 3;
    int oh   = gw >> 7;                      // 0..15
    int cc   = cic * 8;
    int co0  = cog * 2;
    int ih0  = 2 * oh - 1;

    float acc[2][12];
#pragma unroll
    for (int j = 0; j < 2; ++j)
#pragma unroll
        for (int p = 0; p < 12; ++p) acc[j][p] = 0.f;

    const float* wb = w + ((size_t)co0 * 32 + cc) * 16;

#pragma unroll 1
    for (int ci = 0; ci < 8; ++ci) {
        const float* pl = in_t + (size_t)(cc + ci) * 768 * 64 + lane;
        float wr[2][16];
#pragma unroll
        for (int k = 0; k < 16; ++k) {
            wr[0][k] = wb[(0 * 32 + ci) * 16 + k];
            wr[1][k] = wb[(1 * 32 + ci) * 16 + k];
        }
#pragma unroll
        for (int kh = 0; kh < 4; ++kh) {
            int ih = ih0 + kh;
            float p[26];
            p[0] = 0.f; p[25] = 0.f;
            if ((unsigned)ih < 32u) {
#pragma unroll
                for (int c = 0; c < 24; ++c)
                    p[c + 1] = pl[(size_t)(ih * 24 + c) * 64];
            } else {
#pragma unroll
                for (int c = 0; c < 24; ++c) p[c + 1] = 0.f;
            }
#pragma unroll
            for (int ow = 0; ow < 12; ++ow) {
#pragma unroll
                for (int kw = 0; kw < 4; ++kw) {
                    float pv = p[2 * ow + kw];
                    acc[0][ow] = fmaf(pv, wr[0][kh * 4 + kw], acc[0][ow]);
                    acc[1][ow] = fmaf(pv, wr[1][kh * 4 + kw], acc[1][ow]);
                }
            }
        }
    }

    // pbuf[(s*4096 + n*64 + co) * 192 + px], px = oh*12 + ow
    float* pb = pbuf + ((size_t)cic * 4096 + (size_t)lane * 64 + co0) * 192 + oh * 12;
#pragma unroll
    for (int j = 0; j < 2; ++j) {
        float4* o4 = (float4*)(pb + (size_t)j * 192);
        o4[0] = make_float4(acc[j][0], acc[j][1], acc[j][2],  acc[j][3]);
        o4[1] = make_float4(acc[j][4], acc[j][5], acc[j][6],  acc[j][7]);
        o4[2] = make_float4(acc[j][8], acc[j][9], acc[j][10], acc[j][11]);
    }
}

// ---------------------------------------------------------------------------
// L3 reduce: sum 4 splits + instance norm over 192 px + relu, write
// TRANSPOSED [co][px][n] for conv_l4. wave per (n,co). grid 1024, block 256.
// ---------------------------------------------------------------------------
__global__ __launch_bounds__(256) void reduce_norm_l3T(const float* __restrict__ pbuf,
                                                       float* __restrict__ dst_t)
{
    int gid  = blockIdx.x * blockDim.x + threadIdx.x;
    int wv   = gid >> 6;          // 0..4095 = n*64+co
    int lane = gid & 63;
    int n  = wv >> 6;
    int co = wv & 63;
    float tv[3];
#pragma unroll
    for (int k = 0; k < 3; ++k) {
        int i = lane + k * 64;
        float sum = 0.f;
#pragma unroll
        for (int s = 0; s < 4; ++s)
            sum += pbuf[((size_t)s * 4096 + wv) * 192 + i];
        tv[k] = sum;
    }
    float s1 = tv[0] + tv[1] + tv[2];
    float s2 = tv[0]*tv[0] + tv[1]*tv[1] + tv[2]*tv[2];
    for (int m = 32; m >= 1; m >>= 1) {
        s1 += __shfl_xor(s1, m);
        s2 += __shfl_xor(s2, m);
    }
    float mean = s1 * (1.f / 192.f);
    float var  = s2 * (1.f / 192.f) - mean * mean;
    float r = rsqrtf(var + EPS);
#pragma unroll
    for (int k = 0; k < 3; ++k) {
        int i = lane + k * 64;
        float y = fmaxf((tv[k] - mean) * r, 0.f);
        dst_t[((size_t)co * 192 + i) * 64 + n] = y;
    }
}

// ---------------------------------------------------------------------------
// Single-pass instance norm: register-cached float4. HW = TPB*VPT*4. In place.
// ---------------------------------------------------------------------------
template<int TPB, int VPT>
__global__ void inorm_blockv(float* __restrict__ data, int relu)
{
    const int HW = TPB * VPT * 4;
    float4* p = (float4*)(data + (size_t)blockIdx.x * HW);
    float4 v[VPT];
    float s = 0.f, q = 0.f;
#pragma unroll
    for (int k = 0; k < VPT; ++k) {
        v[k] = p[threadIdx.x + k * TPB];
        s += v[k].x + v[k].y + v[k].z + v[k].w;
        q += v[k].x*v[k].x + v[k].y*v[k].y + v[k].z*v[k].z + v[k].w*v[k].w;
    }
    for (int m2 = 32; m2 >= 1; m2 >>= 1) {
        s += __shfl_xor(s, m2);
        q += __shfl_xor(q, m2);
    }
    __shared__ float ss[TPB / 64], sq[TPB / 64], sm[2];
    int wave = threadIdx.x >> 6, lane = threadIdx.x & 63;
    if (lane == 0) { ss[wave] = s; sq[wave] = q; }
    __syncthreads();
    if (threadIdx.x == 0) {
        float a = 0.f, b2 = 0.f;
#pragma unroll
        for (int k = 0; k < TPB / 64; ++k) { a += ss[k]; b2 += sq[k]; }
        float mm = a / (float)HW;
        float vv = b2 / (float)HW - mm * mm;
        sm[0] = mm; sm[1] = rsqrtf(vv + EPS);
    }
    __syncthreads();
    float m = sm[0], r = sm[1];
#pragma unroll
    for (int k = 0; k < VPT; ++k) {
        float4 y;
        y.x = (v[k].x - m) * r; y.y = (v[k].y - m) * r;
        y.z = (v[k].z - m) * r; y.w = (v[k].w - m) * r;
        if (relu) {
            y.x = fmaxf(y.x, 0.f); y.y = fmaxf(y.y, 0.f);
            y.z = fmaxf(y.z, 0.f); y.w = fmaxf(y.w, 0.f);
        }
        p[threadIdx.x + k * TPB] = y;
    }
}

// ---------------------------------------------------------------------------
// L4: (64,16,12)->(128,8,6). Input transposed [ci][px(192)][n(64)].
// ---------------------------------------------------------------------------
__global__ __launch_bounds__(256) void conv_l4(const float* __restrict__ in_t,
                                               const float* __restrict__ w,
                                               float* __restrict__ pbuf)
{
    int t    = threadIdx.x;
    int lane = t & 63;                      // = n
    int gw   = __builtin_amdgcn_readfirstlane(blockIdx.x * 4 + (t >> 6)); // 0..1023
    int cog  = gw & 63;
    int cic  = (gw >> 6) & 7;
    int half = gw >> 9;
    int cc   = cic * 8;
    int co0  = cog * 2;
    int oh0  = half * 4;

    float acc[2][24];
#pragma unroll
    for (int j = 0; j < 2; ++j)
#pragma unroll
        for (int p = 0; p < 24; ++p) acc[j][p] = 0.f;

    const float* wp = w + ((size_t)co0 * 64 + cc) * 16;

#pragma unroll 1
    for (int ci = 0; ci < 8; ++ci) {
        const float* pl = in_t + (size_t)(cc + ci) * 192 * 64 + lane;
        float wr[2][16];
#pragma unroll
        for (int k = 0; k < 16; ++k) {
            wr[0][k] = wp[(0 * 64 + ci) * 16 + k];
            wr[1][k] = wp[(1 * 64 + ci) * 16 + k];
        }
#pragma unroll
        for (int kh = 0; kh < 4; ++kh) {
            float p[4][12];
#pragma unroll
            for (int o = 0; o < 4; ++o) {
                int ih = 2 * (oh0 + o) - 1 + kh;
                if ((unsigned)ih < 16u) {
#pragma unroll
                    for (int c = 0; c < 12; ++c)
                        p[o][c] = pl[(size_t)(ih * 12 + c) * 64];
                } else {
#pragma unroll
                    for (int c = 0; c < 12; ++c) p[o][c] = 0.f;
                }
            }
#pragma unroll
            for (int o = 0; o < 4; ++o)
#pragma unroll
                for (int ow = 0; ow < 6; ++ow) {
#pragma unroll
                    for (int kw = 0; kw < 4; ++kw) {
                        int iw = 2 * ow - 1 + kw;
                        if (iw < 0 || iw >= 12) continue;
                        float pv = p[o][iw];
                        acc[0][o * 6 + ow] = fmaf(pv, wr[0][kh * 4 + kw], acc[0][o * 6 + ow]);
                        acc[1][o * 6 + ow] = fmaf(pv, wr[1][kh * 4 + kw], acc[1][o * 6 + ow]);
                    }
                }
        }
    }

    float* pb = pbuf + ((size_t)(cic * 64 + lane) * 128 + co0) * 48 + oh0 * 6;
#pragma unroll
    for (int j = 0; j < 2; ++j) {
        float4* o4 = (float4*)(pb + j * 48);
#pragma unroll
        for (int q = 0; q < 6; ++q)
            o4[q] = make_float4(acc[j][q * 4 + 0], acc[j][q * 4 + 1],
                                acc[j][q * 4 + 2], acc[j][q * 4 + 3]);
    }
}

__global__ __launch_bounds__(256) void reduce_norm48(const float* __restrict__ pbuf,
                                                     float* __restrict__ out)
{
    int g  = blockIdx.x * blockDim.x + threadIdx.x;   // 8192 threads
    int co = g & 127;
    int n  = g >> 7;
    float s[48];
#pragma unroll
    for (int p = 0; p < 48; ++p) s[p] = 0.f;
#pragma unroll 1
    for (int c = 0; c < 8; ++c) {
        const float4* p4 = (const float4*)(pbuf + ((size_t)(c * 64 + n) * 128 + co) * 48);
#pragma unroll
        for (int q = 0; q < 12; ++q) {
            float4 a = p4[q];
            s[q * 4 + 0] += a.x; s[q * 4 + 1] += a.y;
            s[q * 4 + 2] += a.z; s[q * 4 + 3] += a.w;
        }
    }
    float m = 0.f;
#pragma unroll
    for (int p = 0; p < 48; ++p) m += s[p];
    m *= (1.f / 48.f);
    float q = 0.f;
#pragma unroll
    for (int p = 0; p < 48; ++p) { float d = s[p] - m; q += d * d; }
    q *= (1.f / 48.f);
    float r = rsqrtf(q + EPS);
    float4* o4 = (float4*)(out + ((size_t)n * 128 + co) * 48);
#pragma unroll
    for (int qq = 0; qq < 12; ++qq) {
        float4 v;
        v.x = fmaxf((s[qq * 4 + 0] - m) * r, 0.f);
        v.y = fmaxf((s[qq * 4 + 1] - m) * r, 0.f);
        v.z = fmaxf((s[qq * 4 + 2] - m) * r, 0.f);
        v.w = fmaxf((s[qq * 4 + 3] - m) * r, 0.f);
        o4[qq] = v;
    }
}

// ---------------------------------------------------------------------------
// L6/L7: (256,4,3)->(256,4,3), K=3,S=1,P=1. lane=n scheme.
// ---------------------------------------------------------------------------
__global__ __launch_bounds__(256) void conv_l67(const float* __restrict__ in,
                                                const float* __restrict__ w,
                                                float* __restrict__ pbuf)
{
    int t    = threadIdx.x;
    int gw   = __builtin_amdgcn_readfirstlane(blockIdx.x * 4 + (t >> 6));
    int lane = t & 63;
    int cic  = gw >> 6;
    int cog  = gw & 63;
    int cc   = cic * 16;
    int co0  = cog * 4;

    float acc[4][12];
#pragma unroll
    for (int j = 0; j < 4; ++j)
#pragma unroll
        for (int p = 0; p < 12; ++p) acc[j][p] = 0.f;

    const float* ip = in + ((size_t)lane * 256 + cc) * 12;
    const float* wp = w + ((size_t)co0 * 256 + cc) * 9;

#pragma unroll 2
    for (int ci = 0; ci < 16; ++ci) {
        float p[12];
        const float4* p4 = (const float4*)(ip + ci * 12);
        float4 a0 = p4[0], a1 = p4[1], a2 = p4[2];
        p[0] = a0.x; p[1] = a0.y; p[2]  = a0.z; p[3]  = a0.w;
        p[4] = a1.x; p[5] = a1.y; p[6]  = a1.z; p[7]  = a1.w;
        p[8] = a2.x; p[9] = a2.y; p[10] = a2.z; p[11] = a2.w;
#pragma unroll
        for (int j = 0; j < 4; ++j) {
            const float* wj = wp + ((size_t)j * 256 + ci) * 9;
            float wr[9];
#pragma unroll
            for (int k = 0; k < 9; ++k) wr[k] = wj[k];
#pragma unroll
            for (int oh = 0; oh < 4; ++oh)
#pragma unroll
                for (int ow = 0; ow < 3; ++ow)
#pragma unroll
                    for (int kh = 0; kh < 3; ++kh) {
                        int ih = oh - 1 + kh;
                        if (ih < 0 || ih >= 4) continue;
#pragma unroll
                        for (int kw = 0; kw < 3; ++kw) {
                            int iw = ow - 1 + kw;
                            if (iw < 0 || iw >= 3) continue;
                            acc[j][oh * 3 + ow] =
                                fmaf(p[ih * 3 + iw], wr[kh * 3 + kw], acc[j][oh * 3 + ow]);
                        }
                    }
        }
    }

    float* pb = pbuf + ((size_t)(cic * 64 + lane) * 256 + co0) * 12;
#pragma unroll
    for (int j = 0; j < 4; ++j) {
        float4* o4 = (float4*)(pb + j * 12);
        o4[0] = make_float4(acc[j][0], acc[j][1], acc[j][2],  acc[j][3]);
        o4[1] = make_float4(acc[j][4], acc[j][5], acc[j][6],  acc[j][7]);
        o4[2] = make_float4(acc[j][8], acc[j][9], acc[j][10], acc[j][11]);
    }
}

// ---------------------------------------------------------------------------
// L5: (128,8,6)->(256,4,3), K=4,S=2,P=1. lane=n scheme.
// ---------------------------------------------------------------------------
__global__ __launch_bounds__(256) void conv_l5(const float* __restrict__ in,
                                               const float* __restrict__ w,
                                               float* __restrict__ pbuf)
{
    int t    = threadIdx.x;
    int gw   = __builtin_amdgcn_readfirstlane(blockIdx.x * 4 + (t >> 6));
    int lane = t & 63;
    int cic  = gw >> 6;
    int cog  = gw & 63;
    int cc   = cic * 8;
    int co0  = cog * 4;

    float acc[4][12];
#pragma unroll
    for (int j = 0; j < 4; ++j)
#pragma unroll
        for (int p = 0; p < 12; ++p) acc[j][p] = 0.f;

    const float* ip = in + ((size_t)lane * 128 + cc) * 48;
    const float* wp = w + ((size_t)co0 * 128 + cc) * 16;

#pragma unroll 1
    for (int ci = 0; ci < 8; ++ci) {
        float p[48];
        const float4* p4 = (const float4*)(ip + ci * 48);
#pragma unroll
        for (int q = 0; q < 12; ++q) {
            float4 a = p4[q];
            p[q * 4 + 0] = a.x; p[q * 4 + 1] = a.y; p[q * 4 + 2] = a.z; p[q * 4 + 3] = a.w;
        }
#pragma unroll
        for (int j = 0; j < 4; ++j) {
            const float* wj = wp + ((size_t)j * 128 + ci) * 16;
            float wr[16];
#pragma unroll
            for (int k = 0; k < 16; ++k) wr[k] = wj[k];
#pragma unroll
            for (int oh = 0; oh < 4; ++oh)
#pragma unroll
                for (int ow = 0; ow < 3; ++ow) {
                    int ih0 = 2 * oh - 1, iw0 = 2 * ow - 1;
#pragma unroll
                    for (int kh = 0; kh < 4; ++kh) {
                        int ih = ih0 + kh;
                        if (ih < 0 || ih >= 8) continue;
#pragma unroll
                        for (int kw = 0; kw < 4; ++kw) {
                            int iw = iw0 + kw;
                            if (iw < 0 || iw >= 6) continue;
                            acc[j][oh * 3 + ow] =
                                fmaf(p[ih * 6 + iw], wr[kh * 4 + kw], acc[j][oh * 3 + ow]);
                        }
                    }
                }
        }
    }

    float* pb = pbuf + ((size_t)(cic * 64 + lane) * 256 + co0) * 12;
#pragma unroll
    for (int j = 0; j < 4; ++j) {
        float4* o4 = (float4*)(pb + j * 12);
        o4[0] = make_float4(acc[j][0], acc[j][1], acc[j][2],  acc[j][3]);
        o4[1] = make_float4(acc[j][4], acc[j][5], acc[j][6],  acc[j][7]);
        o4[2] = make_float4(acc[j][8], acc[j][9], acc[j][10], acc[j][11]);
    }
}

__global__ __launch_bounds__(256) void reduce_norm12(const float* __restrict__ pbuf,
                                                     float* __restrict__ out)
{
    int g  = blockIdx.x * blockDim.x + threadIdx.x;   // 16384 threads
    int co = g & 255;
    int n  = g >> 8;
    float s[12];
#pragma unroll
    for (int p = 0; p < 12; ++p) s[p] = 0.f;
#pragma unroll 1
    for (int c = 0; c < 16; ++c) {
        const float4* p4 = (const float4*)(pbuf + ((size_t)(c * 64 + n) * 256 + co) * 12);
        float4 a = p4[0], b = p4[1], d = p4[2];
        s[0] += a.x; s[1] += a.y; s[2]  += a.z; s[3]  += a.w;
        s[4] += b.x; s[5] += b.y; s[6]  += b.z; s[7]  += b.w;
        s[8] += d.x; s[9] += d.y; s[10] += d.z; s[11] += d.w;
    }
    float m = 0.f;
#pragma unroll
    for (int p = 0; p < 12; ++p) m += s[p];
    m *= (1.f / 12.f);
    float q = 0.f;
#pragma unroll
    for (int p = 0; p < 12; ++p) { float d = s[p] - m; q += d * d; }
    q *= (1.f / 12.f);
    float r = rsqrtf(q + EPS);
    float* op = out + ((size_t)n * 256 + co) * 12;
    float4* o4 = (float4*)op;
    float y[12];
#pragma unroll
    for (int p = 0; p < 12; ++p) y[p] = fmaxf((s[p] - m) * r, 0.f);
    o4[0] = make_float4(y[0], y[1], y[2],  y[3]);
    o4[1] = make_float4(y[4], y[5], y[6],  y[7]);
    o4[2] = make_float4(y[8], y[9], y[10], y[11]);
}

// maxpool (64,256,4,3) -> (64,512)
__global__ void pool_kernel(const float* __restrict__ in, float* __restrict__ out)
{
    int idx = blockIdx.x * blockDim.x + threadIdx.x;
    if (idx >= 64 * 512) return;
    int f = idx & 511;
    int n = idx >> 9;
    int c = f >> 1;
    int h = f & 1;
    const float* p = in + (((size_t)n * 256 + c) * 4 + h * 2) * 3;
    out[idx] = fmaxf(fmaxf(p[0], p[1]), fmaxf(p[3], p[4]));
}

__global__ void fc1_kernel(const float* __restrict__ in, const float* __restrict__ w,
                           const float* __restrict__ b, float* __restrict__ out)
{
    int idx = blockIdx.x * blockDim.x + threadIdx.x;
    if (idx >= 64 * 128) return;
    int j = idx & 127;
    int n = idx >> 7;
    const float* x  = in + n * 512;
    const float* wr = w + j * 512;
    float acc = b[j];
    for (int f = 0; f < 512; ++f) acc = fmaf(x[f], wr[f], acc);
    out[idx] = fmaxf(acc, 0.f);
}

__global__ void fc2_kernel(const float* __restrict__ in, const float* __restrict__ w,
                           const float* __restrict__ b, float* __restrict__ out)
{
    int idx = blockIdx.x * blockDim.x + threadIdx.x;
    if (idx >= 64 * 50) return;
    int k = idx % 50;
    int n = idx / 50;
    const float* x  = in + n * 128;
    const float* wr = w + k * 128;
    float acc = b[k];
    for (int f = 0; f < 128; ++f) acc = fmaf(x[f], wr[f], acc);
    out[idx] = tanhf(acc);
}

__global__ void loss_kernel(const float* __restrict__ pts, float* __restrict__ out)
{
    __shared__ float acc[4][64];
    int n = threadIdx.x;
    float rx = 0.f, ry = 0.f, cx = 0.f, cy = 0.f;
    {
        const float* g = pts + n * 50;
        for (int r = 0; r < 5; ++r)
            for (int j = 0; j < 3; ++j)
                for (int d = 0; d < 2; ++d) {
                    float a0 = g[(r * 5 + j) * 2 + d];
                    float a1 = g[(r * 5 + j + 1) * 2 + d];
                    float a2 = g[(r * 5 + j + 2) * 2 + d];
                    float d0 = (a1 - a0) * (a1 - a0);
                    float d1 = (a2 - a1) * (a2 - a1);
                    float t = fmaxf(0.08f, fabsf(d1 - d0));
                    if (d == 0) rx += t; else ry += t;
                }
        for (int r = 0; r < 5; ++r)
            for (int j = 0; j < 3; ++j)
                for (int d = 0; d < 2; ++d) {
                    float a0 = g[(j * 5 + r) * 2 + d];
                    float a1 = g[((j + 1) * 5 + r) * 2 + d];
                    float a2 = g[((j + 2) * 5 + r) * 2 + d];
                    float d0 = (a1 - a0) * (a1 - a0);
                    float d1 = (a2 - a1) * (a2 - a1);
                    float t = fmaxf(0.08f, fabsf(d1 - d0));
                    if (d == 0) cx += t; else cy += t;
                }
    }
    acc[0][n] = rx; acc[1][n] = ry; acc[2][n] = cx; acc[3][n] = cy;
    __syncthreads();
    if (n == 0) {
        float s0 = 0.f, s1 = 0.f, s2 = 0.f, s3 = 0.f;
        for (int i = 0; i < 64; ++i) {
            s0 += acc[0][i]; s1 += acc[1][i]; s2 += acc[2][i]; s3 += acc[3][i];
        }
        float inv = 1.0f / (64.0f * 15.0f);
        out[3200] = s0 * inv;
        out[3201] = s1 * inv;
        out[3202] = s2 * inv;
        out[3203] = s3 * inv;
        const float* g = pts;
        float rg = 0.f, cg = 0.f;
        for (int r = 0; r < 5; ++r)
            for (int j = 0; j < 3; ++j) {
                float x0 = g[(r * 5 + j) * 2],     y0 = g[(r * 5 + j) * 2 + 1];
                float x1 = g[(r * 5 + j + 1) * 2], y1 = g[(r * 5 + j + 1) * 2 + 1];
                float x2 = g[(r * 5 + j + 2) * 2], y2 = g[(r * 5 + j + 2) * 2 + 1];
                rg += fabsf((y1 - y0) * (x1 - x2) - (y1 - y2) * (x1 - x0));
            }
        for (int r = 0; r < 5; ++r)
            for (int j = 0; j < 3; ++j) {
                float x0 = g[(j * 5 + r) * 2],       y0 = g[(j * 5 + r) * 2 + 1];
                float x1 = g[((j + 1) * 5 + r) * 2], y1 = g[((j + 1) * 5 + r) * 2 + 1];
                float x2 = g[((j + 2) * 5 + r) * 2], y2 = g[((j + 2) * 5 + r) * 2 + 1];
                cg += fabsf((y1 - y0) * (x1 - x2) - (y1 - y2) * (x1 - x0));
            }
        out[3204] = fmaxf(rg, 0.02f);
        out[3205] = fmaxf(cg, 0.02f);
    }
}

extern "C" void kernel_launch(void* const* d_in, const int* in_sizes, int n_in,
                              void* d_out, int out_size, void* d_ws, size_t ws_size,
                              hipStream_t stream)
{
    const float* x = (const float*)d_in[0];
    const float* w[8], *bia[8];
    for (int i = 0; i < 6; ++i) { w[i] = (const float*)d_in[1 + 2 * i]; bia[i] = (const float*)d_in[2 + 2 * i]; }
    w[6] = (const float*)d_in[13]; bia[6] = (const float*)d_in[14];
    w[7] = (const float*)d_in[15]; bia[7] = (const float*)d_in[16];
    const float* fc1_w = (const float*)d_in[17];
    const float* fc1_b = (const float*)d_in[18];
    const float* fc2_w = (const float*)d_in[19];
    const float* fc2_b = (const float*)d_in[20];
    float* out = (float*)d_out;

    // workspace (floats):
    float* A      = (float*)d_ws;              // [0 .. 6291456)
    float* Bf     = A + 6291456;               // [6291456 .. 9437184)
    float* pooled = Bf + 3145728;
    float* fc1o   = pooled + 32768;
    // A sub-regions:
    //   [0 .. 1572864)        : L2 conv raw out; later At (L3->L4 transposed, 786432) and l4out
    //   [1572864 .. 3145728)  : At2 = L2 normed transposed [ci][px][n], 1572864 floats
    //   [3145728 .. 6291456)  : pbuf3 (L3 partials, 3145728) then pbuf (L4-L7 partials)
    float* At2    = A + 1572864;
    float* pbuf3  = A + 3145728;
    float* At     = A;
    float* l4out  = A + 1048576;
    float* pbuf   = A + 3145728;

    const int N = 64;

    // ---- L0: conv+bias+relu, then norm ----
    conv0<<<1536, 256, 0, stream>>>(x, w[0], bia[0], A);
    inorm_blockv<256, 12><<<N * 8, 256, 0, stream>>>(A, 0);           // HW=12288

    // ---- L1: (8,128,96)->(16,64,48), conv0-style ----
    conv42V<8, 16, 128, 96, 256><<<768, 256, 0, stream>>>(A, w[1], bia[1], Bf, 0);
    inorm_blockv<256, 3><<<N * 16, 256, 0, stream>>>(Bf, 1);          // HW=3072

    // ---- L2: (16,64,48)->(32,32,24), conv0-style; raw out -> A[0..1572864),
    //      norm writes TRANSPOSED [ci][px][n] -> At2 ----
    conv42V<16, 32, 64, 48, 192><<<512, 192, 0, stream>>>(Bf, w[2], bia[2], A, 0);
    inorm_wave_T768<<<512, 256, 0, stream>>>(A, At2);

    // ---- L3: lane=n transposed conv + fused reduce/norm/relu, transposed out ----
    conv_l3t<<<512, 256, 0, stream>>>(At2, w[3], pbuf3);
    reduce_norm_l3T<<<1024, 256, 0, stream>>>(pbuf3, At);

    // ---- L4 ----
    conv_l4<<<256, 256, 0, stream>>>(At, w[4], pbuf);
    reduce_norm48<<<32, 256, 0, stream>>>(pbuf, l4out);

    // ---- L5 ----
    conv_l5<<<256, 256, 0, stream>>>(l4out, w[5], pbuf);
    reduce_norm12<<<64, 256, 0, stream>>>(pbuf, Bf);

    // ---- L6 ----
    conv_l67<<<256, 256, 0, stream>>>(Bf, w[6], pbuf);
    reduce_norm12<<<64, 256, 0, stream>>>(pbuf, A);

    // ---- L7 ----
    conv_l67<<<256, 256, 0, stream>>>(A, w[7], pbuf);
    float* l7out = Bf + 262144;
    reduce_norm12<<<64, 256, 0, stream>>>(pbuf, l7out);

    pool_kernel<<<(64 * 512 + 255) / 256, 256, 0, stream>>>(l7out, pooled);
    fc1_kernel<<<(64 * 128 + 255) / 256, 256, 0, stream>>>(pooled, fc1_w, fc1_b, fc1o);
    fc2_kernel<<<(64 * 50 + 255) / 256, 256, 0, stream>>>(fc1o, fc2_w, fc2_b, out);
    loss_kernel<<<1, 64, 0, stream>>>(out, out);
}